// Round 3
// baseline (258.587 us; speedup 1.0000x reference)
//
#include <hip/hip_runtime.h>
#include <math.h>

#define YAT_EPS (1.0f / 137.0f)

// Logical sizes (fixed): B=2, T=1024, C=1024.
// Attention (faithful to reference transpose): 64 "heads" (d axis),
// per-head dim 16 (h axis), causal, T=1024.
//
// Packed KV region, per b (stride 6291456 u16):
//   KP at +0        : [d][t][kh16|kl16]            (2097152 u16)
//   VP at +2097152  : [d][jt2][hl][quad][h][e]     (2097152 u16)
//   QP at +4194304  : [d][t][qh16|ql16]            (2097152 u16)
//
// GEMM geometry history (keep — two failed experiments triangulate this):
//   R1: 2-phase dbuf @64x128 -> 153us (codegen collapse; no src pipelining)
//   R2: 128x128 (1.5 blk/CU) -> 70us; 64x128 (3 blk/CU) -> 63.5us
//   => latency-bound, TLP-hidden. This round: 32-row tiles, 6/CU (QKV),
//      4/CU (proj).

typedef __bf16 bf16x8 __attribute__((ext_vector_type(8)));
typedef float floatx4 __attribute__((ext_vector_type(4)));
typedef unsigned int uintx4 __attribute__((ext_vector_type(4)));

__device__ __forceinline__ float fast_rcp(float x) {
#if __has_builtin(__builtin_amdgcn_rcpf)
    return __builtin_amdgcn_rcpf(x);
#else
    return 1.0f / x;
#endif
}
__device__ __forceinline__ float fast_exp2(float x) {
#if __has_builtin(__builtin_amdgcn_exp2f)
    return __builtin_amdgcn_exp2f(x);
#else
    return exp2f(x);
#endif
}

__device__ __forceinline__ unsigned short f32_bf16(float f) {
    unsigned u = __builtin_bit_cast(unsigned, f);
    u += 0x7fffu + ((u >> 16) & 1u);      // RNE; inputs are finite/normal
    return (unsigned short)(u >> 16);
}
__device__ __forceinline__ float bf16_f32(unsigned short h) {
    unsigned u = ((unsigned)h) << 16;
    return __builtin_bit_cast(float, u);
}

// ---------------------------------------------------------------------------
// Merged prep: one dispatch, three block-range sections (K=1024 throughout).
//  bid <  3072 : w_qkv -> WtQh/WtQl (PERMUTED rows) + k2q (atomic)
//  bid <  4096 : w_proj -> WtPh/WtPl + k2p (atomic)
//  bid >= 4096 : x row -> xh/xl bf16 hi/lo + x2x[row]
// Permutation (qkv only): n' = s*1024 + (d>>3)*128 + h*8 + (d&7) so a GEMM
// n-block covers (one s, all 16 h, 8 d) — required by the pack epilogue.
// ---------------------------------------------------------------------------
__global__ __launch_bounds__(256) void prep_kernel(
    const float* __restrict__ x,
    const float* __restrict__ w_qkv, const float* __restrict__ w_proj,
    unsigned short* __restrict__ xh, unsigned short* __restrict__ xl,
    float* __restrict__ x2x,
    unsigned short* __restrict__ WtQh, unsigned short* __restrict__ WtQl,
    float* __restrict__ k2q,
    unsigned short* __restrict__ WtPh, unsigned short* __restrict__ WtPl,
    float* __restrict__ k2p)
{
    __shared__ float t[32][33];
    const int bid = blockIdx.x;
    const int tid = threadIdx.x;

    if (bid < 4096) {
        const bool isQ = bid < 3072;
        const float* W = isQ ? w_qkv : w_proj;
        unsigned short* th = isQ ? WtQh : WtPh;
        unsigned short* tl = isQ ? WtQl : WtPl;
        float* k2 = isQ ? k2q : k2p;
        const int N = isQ ? 3072 : 1024;
        const int id2 = isQ ? bid : bid - 3072;
        const int nx = isQ ? (id2 % 96) : (id2 & 31);
        const int ky = isQ ? (id2 / 96) : (id2 >> 5);
        const int tx = tid & 31, ty = tid >> 5;
        const int n0 = nx * 32, k0 = ky * 32;
        #pragma unroll
        for (int r = 0; r < 4; ++r)
            t[ty + r * 8][tx] = W[(size_t)(k0 + ty + r * 8) * N + n0 + tx];
        __syncthreads();
        #pragma unroll
        for (int r = 0; r < 4; ++r) {
            const int nl = ty + r * 8;
            const int nn = n0 + nl;
            int nw = nn;
            if (isQ) {
                nw = (nn & ~1023) | (((nn & 63) >> 3) << 7)
                   | (((nn >> 6) & 15) << 3) | (nn & 7);
            }
            const float v = t[tx][nl];
            const unsigned short h = f32_bf16(v);
            th[(size_t)nw * 1024 + k0 + tx] = h;
            tl[(size_t)nw * 1024 + k0 + tx] = f32_bf16(v - bf16_f32(h));
            float s = v * v;
            #pragma unroll
            for (int m = 16; m > 0; m >>= 1) s += __shfl_xor(s, m, 32);
            if (tx == 0) atomicAdd(&k2[nn], s);
        }
    } else {
        const int row = bid - 4096;
        float* red = &t[0][0];
        float4 v = *(const float4*)(x + (size_t)row * 1024 + tid * 4);
        float vv[4] = {v.x, v.y, v.z, v.w};
        unsigned short hh[4], ll[4];
        float s = 0.0f;
        #pragma unroll
        for (int e = 0; e < 4; ++e) {
            hh[e] = f32_bf16(vv[e]);
            ll[e] = f32_bf16(vv[e] - bf16_f32(hh[e]));
            s = fmaf(vv[e], vv[e], s);
        }
        *(ushort4*)(xh + (size_t)row * 1024 + tid * 4) =
            make_ushort4(hh[0], hh[1], hh[2], hh[3]);
        *(ushort4*)(xl + (size_t)row * 1024 + tid * 4) =
            make_ushort4(ll[0], ll[1], ll[2], ll[3]);
        #pragma unroll
        for (int off = 32; off > 0; off >>= 1) s += __shfl_down(s, off, 64);
        if ((tid & 63) == 0) red[tid >> 6] = s;
        __syncthreads();
        if (tid == 0) x2x[row] = red[0] + red[1] + red[2] + red[3];
    }
}

// ---------------------------------------------------------------------------
// Split-bf16 MFMA YAT-dense GEMM, templated BM x BN, BK=32, single-buffered
// (R1: source-level double-buffering regressed 2.4x — do not re-add).
// 4 waves in a 2x2 grid, each owning a (BM/2)x(BN/2) sub-tile.
// MODE 0: row-major fp32 store.
// MODE 2: QKV (BN=128 required) — B is the PERMUTED Wt; epilogue packs
//         Q/K/V bf16 hi/lo into kvu + q2k/k2k via LDS transpose, in
//         BM/32 row-groups (G==1 handled: both wm halves write).
// ---------------------------------------------------------------------------
template <int BM, int BN, int MODE>
__global__ __launch_bounds__(256) void gemm_yat_mfma_kernel(
    const unsigned short* __restrict__ Ah, const unsigned short* __restrict__ Al,
    const unsigned short* __restrict__ Bh, const unsigned short* __restrict__ Bl,
    const float* __restrict__ bias, const float* __restrict__ x2,
    const float* __restrict__ k2, const float* __restrict__ alphap,
    float* __restrict__ out, int N, int K, float scale_base,
    unsigned short* __restrict__ kvu, float* __restrict__ q2k,
    float* __restrict__ k2k)
{
    constexpr int TM = (BM / 2) / 16;
    constexpr int TN = (BN / 2) / 16;
    constexpr int NI = (BM + BN) / 32;
    __shared__ __align__(16) unsigned short sbuf[BM * 64 + BN * 64];

    const int tid = threadIdx.x;
    const int w = tid >> 6, l = tid & 63;
    const int lane16 = l & 15, quad = l >> 4;
    const int wm = w & 1, wn = w >> 1;
    const int m0 = blockIdx.y * BM, n0 = blockIdx.x * BN;

    floatx4 acc[TM][TN];
    #pragma unroll
    for (int tm = 0; tm < TM; ++tm)
        #pragma unroll
        for (int tn = 0; tn < TN; ++tn)
            acc[tm][tn] = (floatx4){0.f, 0.f, 0.f, 0.f};

    for (int k0 = 0; k0 < K; k0 += 32) {
        __syncthreads();
        #pragma unroll
        for (int i = 0; i < NI; ++i) {
            const int o = (i * 4 + w) * 1024;
            const unsigned short* gp;
            if (o < BM * 128) {
                const unsigned short* g = (o < BM * 64) ? Ah : Al;
                const int oo = o & (BM * 64 - 1);
                gp = g + (size_t)(m0 + (oo >> 6) + (l >> 2)) * K + k0 + (l & 3) * 8;
            } else {
                const int ob = o - BM * 128;
                const unsigned short* g = (ob < BN * 64) ? Bh : Bl;
                const int oo = ob & (BN * 64 - 1);
                gp = g + (size_t)(n0 + (oo >> 6) + (l >> 2)) * K + k0 + (l & 3) * 8;
            }
            __builtin_amdgcn_global_load_lds(
                (const __attribute__((address_space(1))) unsigned int*)gp,
                (__attribute__((address_space(3))) unsigned int*)((char*)sbuf + o),
                16, 0, 0);
        }
        __syncthreads();

        bf16x8 afh[TM], afl[TM], bfh[TN], bfl[TN];
        #pragma unroll
        for (int tm = 0; tm < TM; ++tm) {
            const int base = (wm * (BM / 2) + tm * 16 + lane16) * 32 + quad * 8;
            afh[tm] = *(const bf16x8*)(sbuf + base);
            afl[tm] = *(const bf16x8*)(sbuf + BM * 32 + base);
        }
        #pragma unroll
        for (int tn = 0; tn < TN; ++tn) {
            const int nb = (wn * (BN / 2) + tn * 16 + lane16) * 32 + quad * 8;
            bfh[tn] = *(const bf16x8*)(sbuf + BM * 64 + nb);
            bfl[tn] = *(const bf16x8*)(sbuf + BM * 64 + BN * 32 + nb);
        }
        #pragma unroll
        for (int tm = 0; tm < TM; ++tm)
            #pragma unroll
            for (int tn = 0; tn < TN; ++tn) {
                acc[tm][tn] = __builtin_amdgcn_mfma_f32_16x16x32_bf16(
                    afh[tm], bfh[tn], acc[tm][tn], 0, 0, 0);
                acc[tm][tn] = __builtin_amdgcn_mfma_f32_16x16x32_bf16(
                    afh[tm], bfl[tn], acc[tm][tn], 0, 0, 0);
                acc[tm][tn] = __builtin_amdgcn_mfma_f32_16x16x32_bf16(
                    afl[tm], bfh[tn], acc[tm][tn], 0, 0, 0);
            }
    }

    const float scale = powf(scale_base, alphap[0]);

    if (MODE == 0) {
        #pragma unroll
        for (int tm = 0; tm < TM; ++tm) {
            #pragma unroll
            for (int tn = 0; tn < TN; ++tn) {
                const int n = n0 + wn * (BN / 2) + tn * 16 + lane16;
                const float kk = k2[n];
                const float bb = bias[n];
                const int mrow = m0 + wm * (BM / 2) + tm * 16 + quad * 4;
                #pragma unroll
                for (int r = 0; r < 4; ++r) {
                    const float y = acc[tm][tn][r];
                    const float den = x2[mrow + r] + kk - 2.0f * y + YAT_EPS;
                    out[(size_t)(mrow + r) * N + n] =
                        y * y / den * scale + bb;
                }
            }
        }
    } else {
        // -------- MODE 2: pack epilogue (BN = 128), BM/32 row-groups --------
        constexpr int G = BM / 32;          // 32-row groups
        float* lds = (float*)sbuf;          // 32 x 132 fp32 (16.9 KB)
        const int s_ = n0 >> 10;            // 0=Q 1=K 2=V (block-const)
        const int dblk = (n0 >> 7) & 7;
        const int b_ = m0 >> 10;
        const int tl = tid >> 3;            // 0..31
        const int ddr = tid & 7;            // 0..7
        const int d_glob = dblk * 8 + ddr;

        #pragma unroll
        for (int g = 0; g < G; ++g) {
            __syncthreads();                // also covers K-loop WAR
            if constexpr (G == 1) {
                // 32 rows split across wm halves: each wave writes its 16.
                #pragma unroll
                for (int tn = 0; tn < TN; ++tn) {
                    const int n = n0 + wn * (BN / 2) + tn * 16 + lane16;
                    const int hcol = (n >> 3) & 15;
                    const int norig = (n & ~1023) | (hcol << 6)
                                    | (dblk << 3) | (n & 7);
                    const float kk = k2[norig];
                    const float bb = bias[norig];
                    const int mrow = m0 + wm * 16 + quad * 4;
                    const int tbase = wm * 16 + quad * 4;
                    const int col = wn * (BN / 2) + tn * 16 + lane16;
                    #pragma unroll
                    for (int r = 0; r < 4; ++r) {
                        const float y = acc[0][tn][r];
                        const float den =
                            x2[mrow + r] + kk - 2.0f * y + YAT_EPS;
                        lds[(tbase + r) * 132 + col] =
                            y * y / den * scale + bb;
                    }
                }
            } else {
                constexpr int GH = (G > 1) ? (G / 2) : 1;
                if (wm == g / GH) {
                    const int gl = g % GH;
                    #pragma unroll
                    for (int tm2 = 0; tm2 < 2; ++tm2) {
                        const int tm = gl * 2 + tm2;
                        #pragma unroll
                        for (int tn = 0; tn < TN; ++tn) {
                            const int n = n0 + wn * (BN / 2) + tn * 16 + lane16;
                            const int hcol = (n >> 3) & 15;
                            const int norig = (n & ~1023) | (hcol << 6)
                                            | (dblk << 3) | (n & 7);
                            const float kk = k2[norig];
                            const float bb = bias[norig];
                            const int mrow =
                                m0 + wm * (BM / 2) + tm * 16 + quad * 4;
                            const int tbase = tm2 * 16 + quad * 4;
                            const int col = wn * (BN / 2) + tn * 16 + lane16;
                            #pragma unroll
                            for (int r = 0; r < 4; ++r) {
                                const float y = acc[tm][tn][r];
                                const float den =
                                    x2[mrow + r] + kk - 2.0f * y + YAT_EPS;
                                lds[(tbase + r) * 132 + col] =
                                    y * y / den * scale + bb;
                            }
                        }
                    }
                }
            }
            __syncthreads();

            float y[16];
            #pragma unroll
            for (int h = 0; h < 16; ++h)
                y[h] = lds[tl * 132 + h * 8 + ddr];
            const int t_glob = (m0 & 1023) + g * 32 + tl;

            if (s_ < 2) {
                unsigned short hb[16], lb[16];
                float s2 = 0.f;
                #pragma unroll
                for (int h = 0; h < 16; ++h) {
                    hb[h] = f32_bf16(y[h]);
                    lb[h] = f32_bf16(y[h] - bf16_f32(hb[h]));
                    s2 = fmaf(y[h], y[h], s2);
                }
                unsigned short* dst = kvu + (size_t)b_ * 6291456
                    + (s_ == 0 ? 4194304u : 0u)
                    + ((size_t)(d_glob * 1024 + t_glob)) * 32;
                #pragma unroll
                for (int h4 = 0; h4 < 4; ++h4) {
                    *(ushort4*)(dst + h4 * 4) = make_ushort4(
                        hb[h4*4], hb[h4*4+1], hb[h4*4+2], hb[h4*4+3]);
                    *(ushort4*)(dst + 16 + h4 * 4) = make_ushort4(
                        lb[h4*4], lb[h4*4+1], lb[h4*4+2], lb[h4*4+3]);
                }
                float* sq = (s_ == 0) ? q2k : k2k;
                sq[b_ * 65536 + d_glob * 1024 + t_glob] = s2;
            } else {
                const int j = t_glob;
                const int jt2 = j >> 5;
                const int e = ((j >> 4) & 1) * 4 + (j & 3);
                const int qd = (j >> 2) & 3;
                unsigned short* dst = kvu + (size_t)b_ * 6291456 + 2097152
                    + d_glob * 32768 + jt2 * 1024 + qd * 128 + e;
                #pragma unroll
                for (int h = 0; h < 16; ++h) {
                    const unsigned short vh = f32_bf16(y[h]);
                    dst[h * 8] = vh;
                    dst[512 + h * 8] = f32_bf16(y[h] - bf16_f32(vh));
                }
            }
        }
    }
}

// ---------------------------------------------------------------------------
// Transpose-free MFMA flash attention (R9 structure; trunc-pack for P).
// S^T = K.Q^T leaves S with i=lane16, j=quad*4+r — the A-operand layout for
// P.V.  P packed to bf16 hi/lo in registers; zero LDS, zero barriers.
// Wave owns i-tiles (ti0, 63-ti0) in the same jt2 loop sharing K/V frags.
// ---------------------------------------------------------------------------
__global__ __launch_bounds__(256) void yat_attn_mfma2_kernel(
    const unsigned short* __restrict__ KVU,
    const float* __restrict__ k2k, const float* __restrict__ q2k,
    const float* __restrict__ alphap,
    unsigned short* __restrict__ attn_h, unsigned short* __restrict__ attn_l,
    float* __restrict__ x2a)
{
    const int tid = threadIdx.x;
    const int lane = tid & 63, w = tid >> 6;
    const int lane16 = lane & 15, quad = lane >> 4;
    const int d = blockIdx.x, c = blockIdx.y, b = blockIdx.z;

    const float isc =
        powf(64.0f / log1pf(64.0f), alphap[0]) * 1.44269504f;  // log2 domain

    const unsigned short* kp = KVU + (size_t)b * 6291456 + d * 32768;
    const unsigned short* vp = KVU + (size_t)b * 6291456 + 2097152 + d * 32768;
    const unsigned short* qp = KVU + (size_t)b * 6291456 + 4194304 + d * 32768;
    const float* k2bd = k2k + b * 65536 + d * 1024;
    const float* q2bd = q2k + b * 65536 + d * 1024;

    const int ti0 = c * 4 + w;            // 0..31
    const int tiA = ti0, tiB = 63 - ti0;

    const bf16x8 qA = *(const bf16x8*)(qp + (tiA * 16 + lane16) * 32 + quad * 8);
    const bf16x8 qB = *(const bf16x8*)(qp + (tiB * 16 + lane16) * 32 + quad * 8);
    const float q2A = q2bd[tiA * 16 + lane16] + YAT_EPS;
    const float q2B = q2bd[tiB * 16 + lane16] + YAT_EPS;
    const int iA = tiA * 16 + lane16;
    const int iB = tiB * 16 + lane16;

    floatx4 OA = (floatx4){0.f, 0.f, 0.f, 0.f};
    floatx4 OB = (floatx4){0.f, 0.f, 0.f, 0.f};
    float lsA = 0.f, lsB = 0.f;

    const int lastA = tiA >> 1, lastB = tiB >> 1;

    for (int jt2 = 0; jt2 <= lastB; ++jt2) {
        const int j0 = jt2 * 32;
        const unsigned short* kp0 = kp + (j0 + lane16) * 32;
        const unsigned short* kp1 = kp + (j0 + 16 + lane16) * 32;
        const bf16x8 k0a = *(const bf16x8*)(kp0 + quad * 8);
        const bf16x8 k0b = *(const bf16x8*)(kp0 + ((quad ^ 2) * 8));
        const bf16x8 k1a = *(const bf16x8*)(kp1 + quad * 8);
        const bf16x8 k1b = *(const bf16x8*)(kp1 + ((quad ^ 2) * 8));
        const unsigned short* vpj = vp + jt2 * 1024 + quad * 128 + lane16 * 8;
        const bf16x8 vh = *(const bf16x8*)(vpj);
        const bf16x8 vl = *(const bf16x8*)(vpj + 512);
        const float4 k20 = *(const float4*)(k2bd + j0 + quad * 4);
        const float4 k21 = *(const float4*)(k2bd + j0 + 16 + quad * 4);
        const float k2r[8] = {k20.x, k20.y, k20.z, k20.w,
                              k21.x, k21.y, k21.z, k21.w};
        const int jbase0 = j0 + quad * 4;

        #pragma unroll
        for (int half = 0; half < 2; ++half) {
            if (half == 0 && jt2 > lastA) continue;
            const bf16x8 qf = half ? qB : qA;
            const float q2e = half ? q2B : q2A;
            const int iM = half ? iB : iA;
            floatx4 S0 = __builtin_amdgcn_mfma_f32_16x16x32_bf16(
                k0a, qf, (floatx4){0.f, 0.f, 0.f, 0.f}, 0, 0, 0);
            S0 = __builtin_amdgcn_mfma_f32_16x16x32_bf16(k0b, qf, S0, 0, 0, 0);
            floatx4 S1 = __builtin_amdgcn_mfma_f32_16x16x32_bf16(
                k1a, qf, (floatx4){0.f, 0.f, 0.f, 0.f}, 0, 0, 0);
            S1 = __builtin_amdgcn_mfma_f32_16x16x32_bf16(k1b, qf, S1, 0, 0, 0);

            float p[8], lsum = 0.f;
            #pragma unroll
            for (int e = 0; e < 8; ++e) {
                const float s = (e < 4) ? S0[e & 3] : S1[e & 3];
                const int j = jbase0 + (e >> 2) * 16 + (e & 3);
                const float den = fmaf(-2.f, s, q2e + k2r[e]);
                float pe = fast_exp2(s * s * fast_rcp(den) * isc);
                pe = (j <= iM) ? pe : 0.f;
                lsum += pe;
                p[e] = pe;
            }
            if (half) lsB += lsum; else lsA += lsum;

            // pack P -> bf16 hi (trunc) / lo (trunc of exact residual):
            // Ph+Pl ~= p to 2^-16; dropped Pl*vl term ~2^-17.
            unsigned ph32[4], pl32[4];
            #pragma unroll
            for (int e2 = 0; e2 < 4; ++e2) {
                const unsigned b0 = __builtin_bit_cast(unsigned, p[e2 * 2]);
                const unsigned b1 = __builtin_bit_cast(unsigned, p[e2 * 2 + 1]);
                ph32[e2] = (b0 >> 16) | (b1 & 0xFFFF0000u);
                const float f0 = p[e2 * 2] -
                    __builtin_bit_cast(float, b0 & 0xFFFF0000u);
                const float f1 = p[e2 * 2 + 1] -
                    __builtin_bit_cast(float, b1 & 0xFFFF0000u);
                pl32[e2] = (__builtin_bit_cast(unsigned, f0) >> 16) |
                           (__builtin_bit_cast(unsigned, f1) & 0xFFFF0000u);
            }
            const bf16x8 Ph = __builtin_bit_cast(bf16x8,
                (uintx4){ph32[0], ph32[1], ph32[2], ph32[3]});
            const bf16x8 Pl = __builtin_bit_cast(bf16x8,
                (uintx4){pl32[0], pl32[1], pl32[2], pl32[3]});

            floatx4 O = half ? OB : OA;
            O = __builtin_amdgcn_mfma_f32_16x16x32_bf16(Ph, vh, O, 0, 0, 0);
            O = __builtin_amdgcn_mfma_f32_16x16x32_bf16(Pl, vh, O, 0, 0, 0);
            O = __builtin_amdgcn_mfma_f32_16x16x32_bf16(Ph, vl, O, 0, 0, 0);
            if (half) OB = O; else OA = O;
        }
    }

    #pragma unroll
    for (int half = 0; half < 2; ++half) {
        float ls = half ? lsB : lsA;
        const floatx4 O = half ? OB : OA;
        const int ti = half ? tiB : tiA;
        ls += __shfl_xor(ls, 16, 64);
        ls += __shfl_xor(ls, 32, 64);
        const float linv = 1.0f / ls;
        #pragma unroll
        for (int r = 0; r < 4; ++r) {
            const float lr = __shfl(linv, quad * 4 + r, 16);
            const float v = O[r] * lr;
            const int i = ti * 16 + quad * 4 + r;
            const size_t off =
                ((size_t)(b * 1024 + i)) * 1024 + d * 16 + lane16;
            const unsigned short vh16 = f32_bf16(v);
            attn_h[off] = vh16;
            attn_l[off] = f32_bf16(v - bf16_f32(vh16));
            float s2 = v * v;
            s2 += __shfl_xor(s2, 1, 64);
            s2 += __shfl_xor(s2, 2, 64);
            s2 += __shfl_xor(s2, 4, 64);
            s2 += __shfl_xor(s2, 8, 64);
            if (lane16 == 0) atomicAdd(&x2a[b * 1024 + i], s2);
        }
    }
}

// ---------------------------------------------------------------------------
extern "C" void kernel_launch(void* const* d_in, const int* in_sizes, int n_in,
                              void* d_out, int out_size, void* d_ws, size_t ws_size,
                              hipStream_t stream)
{
    const float* x          = (const float*)d_in[0];
    // d_in[1] = causal mask, constant — causality hard-coded
    const float* w_qkv      = (const float*)d_in[2];
    const float* b_qkv      = (const float*)d_in[3];
    const float* alpha_qkv  = (const float*)d_in[4];
    const float* w_proj     = (const float*)d_in[5];
    const float* b_proj     = (const float*)d_in[6];
    const float* alpha_proj = (const float*)d_in[7];
    const float* alpha_attn = (const float*)d_in[8];
    float* out = (float*)d_out;

    float* ws = (float*)d_ws;
    unsigned short* KVU  = (unsigned short*)ws;                  // 6291456 f region
    unsigned short* WtQh = (unsigned short*)(ws + 6291456);      // 3072x1024 bf16 (permuted)
    unsigned short* WtQl = (unsigned short*)(ws + 7864320);
    unsigned short* WtPh = (unsigned short*)(ws + 9437184);      // 1024x1024 bf16
    unsigned short* WtPl = (unsigned short*)(ws + 9961472);
    unsigned short* xh   = (unsigned short*)(ws + 10485760);     // 2048x1024 bf16
    unsigned short* xl   = (unsigned short*)(ws + 11534336);
    float* x2x  = ws + 12582912;   // 2048
    float* x2a  = ws + 12584960;   // 2048 (atomic)
    float* k2q  = ws + 12587008;   // 3072 (atomic)
    float* k2p  = ws + 12590080;   // 1024 (atomic)
    float* k2k  = ws + 12591104;   // 131072
    float* q2k  = ws + 12722176;   // 131072   (total 12853248 f = 51.4 MB)
    unsigned short* attn_h = WtQh;             // WtQ dead after QKV GEMM
    unsigned short* attn_l = WtQl;

    // zero atomic accumulators (x2a, k2q, k2p contiguous)
    hipMemsetAsync(x2a, 0, (2048 + 3072 + 1024) * sizeof(float), stream);

    // one merged prep dispatch: both weight transposes + x conversion
    prep_kernel<<<6144, 256, 0, stream>>>(
        x, w_qkv, w_proj, xh, xl, x2x, WtQh, WtQl, k2q, WtPh, WtPl, k2p);

    // QKV GEMM + fused Q/K/V pack (writes KVU, q2k, k2k directly)
    // 32x128 tile: 1536 blocks = 6/CU (TLP hides stage latency; see header)
    const float sb_qkv = sqrtf(3072.0f) / log1pf(3072.0f);
    gemm_yat_mfma_kernel<32, 128, 2><<<dim3(24, 64), 256, 0, stream>>>(
        xh, xl, WtQh, WtQl, b_qkv, x2x, k2q, alpha_qkv, nullptr,
        3072, 1024, sb_qkv, KVU, q2k, k2k);

    yat_attn_mfma2_kernel<<<dim3(64, 8, 2), 256, 0, stream>>>(
        KVU, k2k, q2k, alpha_attn, attn_h, attn_l, x2a);

    // proj: 32x64 tiles -> 1024 blocks = 4/CU (same TLP lever)
    const float sb_proj = sqrtf(1024.0f) / log1pf(1024.0f);
    gemm_yat_mfma_kernel<32, 64, 0><<<dim3(16, 64), 256, 0, stream>>>(
        attn_h, attn_l, WtPh, WtPl, b_proj, x2a, k2p, alpha_proj, out,
        1024, 1024, sb_proj, nullptr, nullptr, nullptr);
}

// Round 4
// 228.201 us; speedup vs baseline: 1.1332x; 1.1332x over previous
//
#include <hip/hip_runtime.h>
#include <math.h>

#define YAT_EPS (1.0f / 137.0f)

// Logical sizes (fixed): B=2, T=1024, C=1024.
// Attention (faithful to reference transpose): 64 "heads" (d axis),
// per-head dim 16 (h axis), causal, T=1024.
//
// Packed KV region, per b (stride 6291456 u16):
//   KP at +0        : [d][t][kh16|kl16]            (2097152 u16)
//   VP at +2097152  : [d][jt2][hl][quad][h][e]     (2097152 u16)
//   QP at +4194304  : [d][t][qh16|ql16]            (2097152 u16)
//
// GEMM experiment history (keep — these triangulate the model):
//   R1: 2-phase dbuf @64x128      -> 153us  (codegen collapse; NO source
//       pipelining grafts on this structure)
//   R2: 128x128 (1.5 blk/CU)      -> 70us
//   R0: 64x128  (3 blk/CU) BK=32  -> 63.5us (best geometry)
//   R3: 32x128  (6 blk/CU)        -> 92us   (2x B-staging; TLP not the fix)
//   => 2-phase critical path = stage+drain+barrier (m233/m252 analog).
//   R4: keep 64x128, BK=64: halve barrier/drain events, same staged bytes.

typedef __bf16 bf16x8 __attribute__((ext_vector_type(8)));
typedef float floatx4 __attribute__((ext_vector_type(4)));
typedef unsigned int uintx4 __attribute__((ext_vector_type(4)));

__device__ __forceinline__ float fast_rcp(float x) {
#if __has_builtin(__builtin_amdgcn_rcpf)
    return __builtin_amdgcn_rcpf(x);
#else
    return 1.0f / x;
#endif
}
__device__ __forceinline__ float fast_exp2(float x) {
#if __has_builtin(__builtin_amdgcn_exp2f)
    return __builtin_amdgcn_exp2f(x);
#else
    return exp2f(x);
#endif
}

__device__ __forceinline__ unsigned short f32_bf16(float f) {
    unsigned u = __builtin_bit_cast(unsigned, f);
    u += 0x7fffu + ((u >> 16) & 1u);      // RNE; inputs are finite/normal
    return (unsigned short)(u >> 16);
}
__device__ __forceinline__ float bf16_f32(unsigned short h) {
    unsigned u = ((unsigned)h) << 16;
    return __builtin_bit_cast(float, u);
}

// ---------------------------------------------------------------------------
// Merged prep: one dispatch, three block-range sections (K=1024 throughout).
//  bid <  3072 : w_qkv -> WtQh/WtQl (PERMUTED rows) + k2q (atomic)
//  bid <  4096 : w_proj -> WtPh/WtPl + k2p (atomic)
//  bid >= 4096 : x row -> xh/xl bf16 hi/lo + x2x[row]
// Permutation (qkv only): n' = s*1024 + (d>>3)*128 + h*8 + (d&7) so a GEMM
// n-block covers (one s, all 16 h, 8 d) — required by the pack epilogue.
// ---------------------------------------------------------------------------
__global__ __launch_bounds__(256) void prep_kernel(
    const float* __restrict__ x,
    const float* __restrict__ w_qkv, const float* __restrict__ w_proj,
    unsigned short* __restrict__ xh, unsigned short* __restrict__ xl,
    float* __restrict__ x2x,
    unsigned short* __restrict__ WtQh, unsigned short* __restrict__ WtQl,
    float* __restrict__ k2q,
    unsigned short* __restrict__ WtPh, unsigned short* __restrict__ WtPl,
    float* __restrict__ k2p)
{
    __shared__ float t[32][33];
    const int bid = blockIdx.x;
    const int tid = threadIdx.x;

    if (bid < 4096) {
        const bool isQ = bid < 3072;
        const float* W = isQ ? w_qkv : w_proj;
        unsigned short* th = isQ ? WtQh : WtPh;
        unsigned short* tl = isQ ? WtQl : WtPl;
        float* k2 = isQ ? k2q : k2p;
        const int N = isQ ? 3072 : 1024;
        const int id2 = isQ ? bid : bid - 3072;
        const int nx = isQ ? (id2 % 96) : (id2 & 31);
        const int ky = isQ ? (id2 / 96) : (id2 >> 5);
        const int tx = tid & 31, ty = tid >> 5;
        const int n0 = nx * 32, k0 = ky * 32;
        #pragma unroll
        for (int r = 0; r < 4; ++r)
            t[ty + r * 8][tx] = W[(size_t)(k0 + ty + r * 8) * N + n0 + tx];
        __syncthreads();
        #pragma unroll
        for (int r = 0; r < 4; ++r) {
            const int nl = ty + r * 8;
            const int nn = n0 + nl;
            int nw = nn;
            if (isQ) {
                nw = (nn & ~1023) | (((nn & 63) >> 3) << 7)
                   | (((nn >> 6) & 15) << 3) | (nn & 7);
            }
            const float v = t[tx][nl];
            const unsigned short h = f32_bf16(v);
            th[(size_t)nw * 1024 + k0 + tx] = h;
            tl[(size_t)nw * 1024 + k0 + tx] = f32_bf16(v - bf16_f32(h));
            float s = v * v;
            #pragma unroll
            for (int m = 16; m > 0; m >>= 1) s += __shfl_xor(s, m, 32);
            if (tx == 0) atomicAdd(&k2[nn], s);
        }
    } else {
        const int row = bid - 4096;
        float* red = &t[0][0];
        float4 v = *(const float4*)(x + (size_t)row * 1024 + tid * 4);
        float vv[4] = {v.x, v.y, v.z, v.w};
        unsigned short hh[4], ll[4];
        float s = 0.0f;
        #pragma unroll
        for (int e = 0; e < 4; ++e) {
            hh[e] = f32_bf16(vv[e]);
            ll[e] = f32_bf16(vv[e] - bf16_f32(hh[e]));
            s = fmaf(vv[e], vv[e], s);
        }
        *(ushort4*)(xh + (size_t)row * 1024 + tid * 4) =
            make_ushort4(hh[0], hh[1], hh[2], hh[3]);
        *(ushort4*)(xl + (size_t)row * 1024 + tid * 4) =
            make_ushort4(ll[0], ll[1], ll[2], ll[3]);
        #pragma unroll
        for (int off = 32; off > 0; off >>= 1) s += __shfl_down(s, off, 64);
        if ((tid & 63) == 0) red[tid >> 6] = s;
        __syncthreads();
        if (tid == 0) x2x[row] = red[0] + red[1] + red[2] + red[3];
    }
}

// ---------------------------------------------------------------------------
// Split-bf16 MFMA YAT-dense GEMM, templated BM x BN x BK, single-buffered
// (R1: source-level double-buffering regressed 2.4x — do not re-add).
// 4 waves in a 2x2 grid, each owning a (BM/2)x(BN/2) sub-tile.
// BK=64: two K-subtiles per stage; halves barrier/drain events (the 2-phase
// critical path) at unchanged total staged bytes.
// MODE 0: row-major fp32 store.
// MODE 2: QKV (BN=128 required) — B is the PERMUTED Wt; epilogue packs
//         Q/K/V bf16 hi/lo into kvu + q2k/k2k via LDS transpose, in
//         BM/32 row-groups.
// ---------------------------------------------------------------------------
template <int BM, int BN, int BK, int MODE>
__global__ __launch_bounds__(256) void gemm_yat_mfma_kernel(
    const unsigned short* __restrict__ Ah, const unsigned short* __restrict__ Al,
    const unsigned short* __restrict__ Bh, const unsigned short* __restrict__ Bl,
    const float* __restrict__ bias, const float* __restrict__ x2,
    const float* __restrict__ k2, const float* __restrict__ alphap,
    float* __restrict__ out, int N, int K, float scale_base,
    unsigned short* __restrict__ kvu, float* __restrict__ q2k,
    float* __restrict__ k2k)
{
    constexpr int TM = (BM / 2) / 16;
    constexpr int TN = (BN / 2) / 16;
    constexpr int ASZ = BM * BK;             // u16 per A region (hi or lo)
    constexpr int BSZ = BN * BK;             // u16 per B region
    constexpr int AB  = ASZ * 2;             // bytes per A region (pow2)
    constexpr int BB  = BSZ * 2;             // bytes per B region (pow2)
    constexpr int NI  = (BM + BN) * BK / 1024;   // global_load_lds per thread
    constexpr int LPR = BK / 8;              // lanes per staged row
    __shared__ __align__(16) unsigned short sbuf[2 * (ASZ + BSZ)];

    const int tid = threadIdx.x;
    const int w = tid >> 6, l = tid & 63;
    const int lane16 = l & 15, quad = l >> 4;
    const int wm = w & 1, wn = w >> 1;
    const int m0 = blockIdx.y * BM, n0 = blockIdx.x * BN;

    floatx4 acc[TM][TN];
    #pragma unroll
    for (int tm = 0; tm < TM; ++tm)
        #pragma unroll
        for (int tn = 0; tn < TN; ++tn)
            acc[tm][tn] = (floatx4){0.f, 0.f, 0.f, 0.f};

    for (int k0 = 0; k0 < K; k0 += BK) {
        __syncthreads();
        #pragma unroll
        for (int i = 0; i < NI; ++i) {
            const int o = (i * 4 + w) * 1024;    // byte offset in LDS
            const unsigned short* gp;
            if (o < 2 * AB) {
                const unsigned short* g = (o < AB) ? Ah : Al;
                const int oo = o & (AB - 1);
                gp = g + (size_t)(m0 + oo / (BK * 2) + l / LPR) * K
                       + k0 + (l % LPR) * 8;
            } else {
                const int ob = o - 2 * AB;
                const unsigned short* g = (ob < BB) ? Bh : Bl;
                const int oo = ob & (BB - 1);
                gp = g + (size_t)(n0 + oo / (BK * 2) + l / LPR) * K
                       + k0 + (l % LPR) * 8;
            }
            __builtin_amdgcn_global_load_lds(
                (const __attribute__((address_space(1))) unsigned int*)gp,
                (__attribute__((address_space(3))) unsigned int*)((char*)sbuf + o),
                16, 0, 0);
        }
        __syncthreads();

        #pragma unroll
        for (int kk = 0; kk < BK / 32; ++kk) {
            bf16x8 afh[TM], afl[TM], bfh[TN], bfl[TN];
            #pragma unroll
            for (int tm = 0; tm < TM; ++tm) {
                const int base = (wm * (BM / 2) + tm * 16 + lane16) * BK
                               + kk * 32 + quad * 8;
                afh[tm] = *(const bf16x8*)(sbuf + base);
                afl[tm] = *(const bf16x8*)(sbuf + ASZ + base);
            }
            #pragma unroll
            for (int tn = 0; tn < TN; ++tn) {
                const int nb = (wn * (BN / 2) + tn * 16 + lane16) * BK
                             + kk * 32 + quad * 8;
                bfh[tn] = *(const bf16x8*)(sbuf + 2 * ASZ + nb);
                bfl[tn] = *(const bf16x8*)(sbuf + 2 * ASZ + BSZ + nb);
            }
            #pragma unroll
            for (int tm = 0; tm < TM; ++tm)
                #pragma unroll
                for (int tn = 0; tn < TN; ++tn) {
                    acc[tm][tn] = __builtin_amdgcn_mfma_f32_16x16x32_bf16(
                        afh[tm], bfh[tn], acc[tm][tn], 0, 0, 0);
                    acc[tm][tn] = __builtin_amdgcn_mfma_f32_16x16x32_bf16(
                        afh[tm], bfl[tn], acc[tm][tn], 0, 0, 0);
                    acc[tm][tn] = __builtin_amdgcn_mfma_f32_16x16x32_bf16(
                        afl[tm], bfh[tn], acc[tm][tn], 0, 0, 0);
                }
        }
    }

    const float scale = powf(scale_base, alphap[0]);

    if (MODE == 0) {
        #pragma unroll
        for (int tm = 0; tm < TM; ++tm) {
            #pragma unroll
            for (int tn = 0; tn < TN; ++tn) {
                const int n = n0 + wn * (BN / 2) + tn * 16 + lane16;
                const float kk = k2[n];
                const float bb = bias[n];
                const int mrow = m0 + wm * (BM / 2) + tm * 16 + quad * 4;
                #pragma unroll
                for (int r = 0; r < 4; ++r) {
                    const float y = acc[tm][tn][r];
                    const float den = x2[mrow + r] + kk - 2.0f * y + YAT_EPS;
                    out[(size_t)(mrow + r) * N + n] =
                        y * y / den * scale + bb;
                }
            }
        }
    } else {
        // -------- MODE 2: pack epilogue (BN = 128), BM/32 row-groups --------
        constexpr int G = BM / 32;          // 32-row groups
        float* lds = (float*)sbuf;          // 32 x 132 fp32 (16.9 KB)
        const int s_ = n0 >> 10;            // 0=Q 1=K 2=V (block-const)
        const int dblk = (n0 >> 7) & 7;
        const int b_ = m0 >> 10;
        const int tl = tid >> 3;            // 0..31
        const int ddr = tid & 7;            // 0..7
        const int d_glob = dblk * 8 + ddr;

        #pragma unroll
        for (int g = 0; g < G; ++g) {
            __syncthreads();                // also covers K-loop WAR
            if constexpr (G == 1) {
                #pragma unroll
                for (int tn = 0; tn < TN; ++tn) {
                    const int n = n0 + wn * (BN / 2) + tn * 16 + lane16;
                    const int hcol = (n >> 3) & 15;
                    const int norig = (n & ~1023) | (hcol << 6)
                                    | (dblk << 3) | (n & 7);
                    const float kk = k2[norig];
                    const float bb = bias[norig];
                    const int mrow = m0 + wm * 16 + quad * 4;
                    const int tbase = wm * 16 + quad * 4;
                    const int col = wn * (BN / 2) + tn * 16 + lane16;
                    #pragma unroll
                    for (int r = 0; r < 4; ++r) {
                        const float y = acc[0][tn][r];
                        const float den =
                            x2[mrow + r] + kk - 2.0f * y + YAT_EPS;
                        lds[(tbase + r) * 132 + col] =
                            y * y / den * scale + bb;
                    }
                }
            } else {
                constexpr int GH = (G > 1) ? (G / 2) : 1;
                if (wm == g / GH) {
                    const int gl = g % GH;
                    #pragma unroll
                    for (int tm2 = 0; tm2 < 2; ++tm2) {
                        const int tm = gl * 2 + tm2;
                        #pragma unroll
                        for (int tn = 0; tn < TN; ++tn) {
                            const int n = n0 + wn * (BN / 2) + tn * 16 + lane16;
                            const int hcol = (n >> 3) & 15;
                            const int norig = (n & ~1023) | (hcol << 6)
                                            | (dblk << 3) | (n & 7);
                            const float kk = k2[norig];
                            const float bb = bias[norig];
                            const int mrow =
                                m0 + wm * (BM / 2) + tm * 16 + quad * 4;
                            const int tbase = tm2 * 16 + quad * 4;
                            const int col = wn * (BN / 2) + tn * 16 + lane16;
                            #pragma unroll
                            for (int r = 0; r < 4; ++r) {
                                const float y = acc[tm][tn][r];
                                const float den =
                                    x2[mrow + r] + kk - 2.0f * y + YAT_EPS;
                                lds[(tbase + r) * 132 + col] =
                                    y * y / den * scale + bb;
                            }
                        }
                    }
                }
            }
            __syncthreads();

            float y[16];
            #pragma unroll
            for (int h = 0; h < 16; ++h)
                y[h] = lds[tl * 132 + h * 8 + ddr];
            const int t_glob = (m0 & 1023) + g * 32 + tl;

            if (s_ < 2) {
                unsigned short hb[16], lb[16];
                float s2 = 0.f;
                #pragma unroll
                for (int h = 0; h < 16; ++h) {
                    hb[h] = f32_bf16(y[h]);
                    lb[h] = f32_bf16(y[h] - bf16_f32(hb[h]));
                    s2 = fmaf(y[h], y[h], s2);
                }
                unsigned short* dst = kvu + (size_t)b_ * 6291456
                    + (s_ == 0 ? 4194304u : 0u)
                    + ((size_t)(d_glob * 1024 + t_glob)) * 32;
                #pragma unroll
                for (int h4 = 0; h4 < 4; ++h4) {
                    *(ushort4*)(dst + h4 * 4) = make_ushort4(
                        hb[h4*4], hb[h4*4+1], hb[h4*4+2], hb[h4*4+3]);
                    *(ushort4*)(dst + 16 + h4 * 4) = make_ushort4(
                        lb[h4*4], lb[h4*4+1], lb[h4*4+2], lb[h4*4+3]);
                }
                float* sq = (s_ == 0) ? q2k : k2k;
                sq[b_ * 65536 + d_glob * 1024 + t_glob] = s2;
            } else {
                const int j = t_glob;
                const int jt2 = j >> 5;
                const int e = ((j >> 4) & 1) * 4 + (j & 3);
                const int qd = (j >> 2) & 3;
                unsigned short* dst = kvu + (size_t)b_ * 6291456 + 2097152
                    + d_glob * 32768 + jt2 * 1024 + qd * 128 + e;
                #pragma unroll
                for (int h = 0; h < 16; ++h) {
                    const unsigned short vh = f32_bf16(y[h]);
                    dst[h * 8] = vh;
                    dst[512 + h * 8] = f32_bf16(y[h] - bf16_f32(vh));
                }
            }
        }
    }
}

// ---------------------------------------------------------------------------
// Transpose-free MFMA flash attention (R9 structure; trunc-pack for P).
// S^T = K.Q^T leaves S with i=lane16, j=quad*4+r — the A-operand layout for
// P.V.  P packed to bf16 hi/lo in registers; zero LDS, zero barriers.
// Wave owns i-tiles (ti0, 63-ti0) in the same jt2 loop sharing K/V frags.
// ---------------------------------------------------------------------------
__global__ __launch_bounds__(256) void yat_attn_mfma2_kernel(
    const unsigned short* __restrict__ KVU,
    const float* __restrict__ k2k, const float* __restrict__ q2k,
    const float* __restrict__ alphap,
    unsigned short* __restrict__ attn_h, unsigned short* __restrict__ attn_l,
    float* __restrict__ x2a)
{
    const int tid = threadIdx.x;
    const int lane = tid & 63, w = tid >> 6;
    const int lane16 = lane & 15, quad = lane >> 4;
    const int d = blockIdx.x, c = blockIdx.y, b = blockIdx.z;

    const float isc =
        powf(64.0f / log1pf(64.0f), alphap[0]) * 1.44269504f;  // log2 domain

    const unsigned short* kp = KVU + (size_t)b * 6291456 + d * 32768;
    const unsigned short* vp = KVU + (size_t)b * 6291456 + 2097152 + d * 32768;
    const unsigned short* qp = KVU + (size_t)b * 6291456 + 4194304 + d * 32768;
    const float* k2bd = k2k + b * 65536 + d * 1024;
    const float* q2bd = q2k + b * 65536 + d * 1024;

    const int ti0 = c * 4 + w;            // 0..31
    const int tiA = ti0, tiB = 63 - ti0;

    const bf16x8 qA = *(const bf16x8*)(qp + (tiA * 16 + lane16) * 32 + quad * 8);
    const bf16x8 qB = *(const bf16x8*)(qp + (tiB * 16 + lane16) * 32 + quad * 8);
    const float q2A = q2bd[tiA * 16 + lane16] + YAT_EPS;
    const float q2B = q2bd[tiB * 16 + lane16] + YAT_EPS;
    const int iA = tiA * 16 + lane16;
    const int iB = tiB * 16 + lane16;

    floatx4 OA = (floatx4){0.f, 0.f, 0.f, 0.f};
    floatx4 OB = (floatx4){0.f, 0.f, 0.f, 0.f};
    float lsA = 0.f, lsB = 0.f;

    const int lastA = tiA >> 1, lastB = tiB >> 1;

    for (int jt2 = 0; jt2 <= lastB; ++jt2) {
        const int j0 = jt2 * 32;
        const unsigned short* kp0 = kp + (j0 + lane16) * 32;
        const unsigned short* kp1 = kp + (j0 + 16 + lane16) * 32;
        const bf16x8 k0a = *(const bf16x8*)(kp0 + quad * 8);
        const bf16x8 k0b = *(const bf16x8*)(kp0 + ((quad ^ 2) * 8));
        const bf16x8 k1a = *(const bf16x8*)(kp1 + quad * 8);
        const bf16x8 k1b = *(const bf16x8*)(kp1 + ((quad ^ 2) * 8));
        const unsigned short* vpj = vp + jt2 * 1024 + quad * 128 + lane16 * 8;
        const bf16x8 vh = *(const bf16x8*)(vpj);
        const bf16x8 vl = *(const bf16x8*)(vpj + 512);
        const float4 k20 = *(const float4*)(k2bd + j0 + quad * 4);
        const float4 k21 = *(const float4*)(k2bd + j0 + 16 + quad * 4);
        const float k2r[8] = {k20.x, k20.y, k20.z, k20.w,
                              k21.x, k21.y, k21.z, k21.w};
        const int jbase0 = j0 + quad * 4;

        #pragma unroll
        for (int half = 0; half < 2; ++half) {
            if (half == 0 && jt2 > lastA) continue;
            const bf16x8 qf = half ? qB : qA;
            const float q2e = half ? q2B : q2A;
            const int iM = half ? iB : iA;
            floatx4 S0 = __builtin_amdgcn_mfma_f32_16x16x32_bf16(
                k0a, qf, (floatx4){0.f, 0.f, 0.f, 0.f}, 0, 0, 0);
            S0 = __builtin_amdgcn_mfma_f32_16x16x32_bf16(k0b, qf, S0, 0, 0, 0);
            floatx4 S1 = __builtin_amdgcn_mfma_f32_16x16x32_bf16(
                k1a, qf, (floatx4){0.f, 0.f, 0.f, 0.f}, 0, 0, 0);
            S1 = __builtin_amdgcn_mfma_f32_16x16x32_bf16(k1b, qf, S1, 0, 0, 0);

            float p[8], lsum = 0.f;
            #pragma unroll
            for (int e = 0; e < 8; ++e) {
                const float s = (e < 4) ? S0[e & 3] : S1[e & 3];
                const int j = jbase0 + (e >> 2) * 16 + (e & 3);
                const float den = fmaf(-2.f, s, q2e + k2r[e]);
                float pe = fast_exp2(s * s * fast_rcp(den) * isc);
                pe = (j <= iM) ? pe : 0.f;
                lsum += pe;
                p[e] = pe;
            }
            if (half) lsB += lsum; else lsA += lsum;

            // pack P -> bf16 hi (trunc) / lo (trunc of exact residual):
            // Ph+Pl ~= p to 2^-16; dropped Pl*vl term ~2^-17.
            unsigned ph32[4], pl32[4];
            #pragma unroll
            for (int e2 = 0; e2 < 4; ++e2) {
                const unsigned b0 = __builtin_bit_cast(unsigned, p[e2 * 2]);
                const unsigned b1 = __builtin_bit_cast(unsigned, p[e2 * 2 + 1]);
                ph32[e2] = (b0 >> 16) | (b1 & 0xFFFF0000u);
                const float f0 = p[e2 * 2] -
                    __builtin_bit_cast(float, b0 & 0xFFFF0000u);
                const float f1 = p[e2 * 2 + 1] -
                    __builtin_bit_cast(float, b1 & 0xFFFF0000u);
                pl32[e2] = (__builtin_bit_cast(unsigned, f0) >> 16) |
                           (__builtin_bit_cast(unsigned, f1) & 0xFFFF0000u);
            }
            const bf16x8 Ph = __builtin_bit_cast(bf16x8,
                (uintx4){ph32[0], ph32[1], ph32[2], ph32[3]});
            const bf16x8 Pl = __builtin_bit_cast(bf16x8,
                (uintx4){pl32[0], pl32[1], pl32[2], pl32[3]});

            floatx4 O = half ? OB : OA;
            O = __builtin_amdgcn_mfma_f32_16x16x32_bf16(Ph, vh, O, 0, 0, 0);
            O = __builtin_amdgcn_mfma_f32_16x16x32_bf16(Pl, vh, O, 0, 0, 0);
            O = __builtin_amdgcn_mfma_f32_16x16x32_bf16(Ph, vl, O, 0, 0, 0);
            if (half) OB = O; else OA = O;
        }
    }

    #pragma unroll
    for (int half = 0; half < 2; ++half) {
        float ls = half ? lsB : lsA;
        const floatx4 O = half ? OB : OA;
        const int ti = half ? tiB : tiA;
        ls += __shfl_xor(ls, 16, 64);
        ls += __shfl_xor(ls, 32, 64);
        const float linv = 1.0f / ls;
        #pragma unroll
        for (int r = 0; r < 4; ++r) {
            const float lr = __shfl(linv, quad * 4 + r, 16);
            const float v = O[r] * lr;
            const int i = ti * 16 + quad * 4 + r;
            const size_t off =
                ((size_t)(b * 1024 + i)) * 1024 + d * 16 + lane16;
            const unsigned short vh16 = f32_bf16(v);
            attn_h[off] = vh16;
            attn_l[off] = f32_bf16(v - bf16_f32(vh16));
            float s2 = v * v;
            s2 += __shfl_xor(s2, 1, 64);
            s2 += __shfl_xor(s2, 2, 64);
            s2 += __shfl_xor(s2, 4, 64);
            s2 += __shfl_xor(s2, 8, 64);
            if (lane16 == 0) atomicAdd(&x2a[b * 1024 + i], s2);
        }
    }
}

// ---------------------------------------------------------------------------
extern "C" void kernel_launch(void* const* d_in, const int* in_sizes, int n_in,
                              void* d_out, int out_size, void* d_ws, size_t ws_size,
                              hipStream_t stream)
{
    const float* x          = (const float*)d_in[0];
    // d_in[1] = causal mask, constant — causality hard-coded
    const float* w_qkv      = (const float*)d_in[2];
    const float* b_qkv      = (const float*)d_in[3];
    const float* alpha_qkv  = (const float*)d_in[4];
    const float* w_proj     = (const float*)d_in[5];
    const float* b_proj     = (const float*)d_in[6];
    const float* alpha_proj = (const float*)d_in[7];
    const float* alpha_attn = (const float*)d_in[8];
    float* out = (float*)d_out;

    float* ws = (float*)d_ws;
    unsigned short* KVU  = (unsigned short*)ws;                  // 6291456 f region
    unsigned short* WtQh = (unsigned short*)(ws + 6291456);      // 3072x1024 bf16 (permuted)
    unsigned short* WtQl = (unsigned short*)(ws + 7864320);
    unsigned short* WtPh = (unsigned short*)(ws + 9437184);      // 1024x1024 bf16
    unsigned short* WtPl = (unsigned short*)(ws + 9961472);
    unsigned short* xh   = (unsigned short*)(ws + 10485760);     // 2048x1024 bf16
    unsigned short* xl   = (unsigned short*)(ws + 11534336);
    float* x2x  = ws + 12582912;   // 2048
    float* x2a  = ws + 12584960;   // 2048 (atomic)
    float* k2q  = ws + 12587008;   // 3072 (atomic)
    float* k2p  = ws + 12590080;   // 1024 (atomic)
    float* k2k  = ws + 12591104;   // 131072
    float* q2k  = ws + 12722176;   // 131072   (total 12853248 f = 51.4 MB)
    unsigned short* attn_h = WtQh;             // WtQ dead after QKV GEMM
    unsigned short* attn_l = WtQl;

    // zero atomic accumulators (x2a, k2q, k2p contiguous)
    hipMemsetAsync(x2a, 0, (2048 + 3072 + 1024) * sizeof(float), stream);

    // one merged prep dispatch: both weight transposes + x conversion
    prep_kernel<<<6144, 256, 0, stream>>>(
        x, w_qkv, w_proj, xh, xl, x2x, WtQh, WtQl, k2q, WtPh, WtPl, k2p);

    // QKV GEMM + fused Q/K/V pack (writes KVU, q2k, k2k directly)
    // 64x128 tile (R0 best geometry), BK=64: 16 barrier pairs instead of 32
    const float sb_qkv = sqrtf(3072.0f) / log1pf(3072.0f);
    gemm_yat_mfma_kernel<64, 128, 64, 2><<<dim3(24, 32), 256, 0, stream>>>(
        xh, xl, WtQh, WtQl, b_qkv, x2x, k2q, alpha_qkv, nullptr,
        3072, 1024, sb_qkv, KVU, q2k, k2k);

    yat_attn_mfma2_kernel<<<dim3(64, 8, 2), 256, 0, stream>>>(
        KVU, k2k, q2k, alpha_attn, attn_h, attn_l, x2a);

    // proj: 64x64 tiles -> 512 blocks (2/CU), BK=64
    const float sb_proj = sqrtf(1024.0f) / log1pf(1024.0f);
    gemm_yat_mfma_kernel<64, 64, 64, 0><<<dim3(16, 32), 256, 0, stream>>>(
        attn_h, attn_l, WtPh, WtPl, b_proj, x2a, k2p, alpha_proj, out,
        1024, 1024, sb_proj, nullptr, nullptr, nullptr);
}

// Round 5
// 227.276 us; speedup vs baseline: 1.1378x; 1.0041x over previous
//
#include <hip/hip_runtime.h>
#include <math.h>

#define YAT_EPS (1.0f / 137.0f)

// Logical sizes (fixed): B=2, T=1024, C=1024.
// Attention (faithful to reference transpose): 64 "heads" (d axis),
// per-head dim 16 (h axis), causal, T=1024.
//
// Packed KV region, per b (stride 6291456 u16):
//   KP at +0        : [d][t][kh16|kl16]            (2097152 u16)
//   VP at +2097152  : [d][jt2][hl][quad][h][e]     (2097152 u16)
//   QP at +4194304  : [d][t][qh16|ql16]            (2097152 u16)
//
// GEMM experiment history (keep — these triangulate the model):
//   R1: 2-phase dbuf @64x128      -> 153us  (codegen collapse; NO source
//       pipelining grafts on this structure)
//   R2: 128x128 (1.5 blk/CU)      -> 70us
//   R0: 64x128  (3 blk/CU) BK=32  -> 63.5us
//   R3: 32x128  (6 blk/CU)        -> 92us   (2x B-staging; TLP not the fix)
//   R4: 64x128 BK=64              -> 63.5us (barriers halved: no change;
//       conflicts 3x'd: no change — both off critical path)
//   R5: QKV pinned at 63.5 with VGPR=72 (compiler targeting occupancy the
//       LDS cap forbids). This round: __launch_bounds__ min-waves = actual
//       blocks/CU -> free ~100 VGPR for address caching / frag prefetch.

typedef __bf16 bf16x8 __attribute__((ext_vector_type(8)));
typedef float floatx4 __attribute__((ext_vector_type(4)));
typedef unsigned int uintx4 __attribute__((ext_vector_type(4)));

__device__ __forceinline__ float fast_rcp(float x) {
#if __has_builtin(__builtin_amdgcn_rcpf)
    return __builtin_amdgcn_rcpf(x);
#else
    return 1.0f / x;
#endif
}
__device__ __forceinline__ float fast_exp2(float x) {
#if __has_builtin(__builtin_amdgcn_exp2f)
    return __builtin_amdgcn_exp2f(x);
#else
    return exp2f(x);
#endif
}

__device__ __forceinline__ unsigned short f32_bf16(float f) {
    unsigned u = __builtin_bit_cast(unsigned, f);
    u += 0x7fffu + ((u >> 16) & 1u);      // RNE; inputs are finite/normal
    return (unsigned short)(u >> 16);
}
__device__ __forceinline__ float bf16_f32(unsigned short h) {
    unsigned u = ((unsigned)h) << 16;
    return __builtin_bit_cast(float, u);
}

// ---------------------------------------------------------------------------
// Merged prep: one dispatch, three block-range sections (K=1024 throughout).
//  bid <  3072 : w_qkv -> WtQh/WtQl (PERMUTED rows) + k2q (atomic)
//  bid <  4096 : w_proj -> WtPh/WtPl + k2p (atomic)
//  bid >= 4096 : x row -> xh/xl bf16 hi/lo + x2x[row]
// Permutation (qkv only): n' = s*1024 + (d>>3)*128 + h*8 + (d&7) so a GEMM
// n-block covers (one s, all 16 h, 8 d) — required by the pack epilogue.
// ---------------------------------------------------------------------------
__global__ __launch_bounds__(256) void prep_kernel(
    const float* __restrict__ x,
    const float* __restrict__ w_qkv, const float* __restrict__ w_proj,
    unsigned short* __restrict__ xh, unsigned short* __restrict__ xl,
    float* __restrict__ x2x,
    unsigned short* __restrict__ WtQh, unsigned short* __restrict__ WtQl,
    float* __restrict__ k2q,
    unsigned short* __restrict__ WtPh, unsigned short* __restrict__ WtPl,
    float* __restrict__ k2p)
{
    __shared__ float t[32][33];
    const int bid = blockIdx.x;
    const int tid = threadIdx.x;

    if (bid < 4096) {
        const bool isQ = bid < 3072;
        const float* W = isQ ? w_qkv : w_proj;
        unsigned short* th = isQ ? WtQh : WtPh;
        unsigned short* tl = isQ ? WtQl : WtPl;
        float* k2 = isQ ? k2q : k2p;
        const int N = isQ ? 3072 : 1024;
        const int id2 = isQ ? bid : bid - 3072;
        const int nx = isQ ? (id2 % 96) : (id2 & 31);
        const int ky = isQ ? (id2 / 96) : (id2 >> 5);
        const int tx = tid & 31, ty = tid >> 5;
        const int n0 = nx * 32, k0 = ky * 32;
        #pragma unroll
        for (int r = 0; r < 4; ++r)
            t[ty + r * 8][tx] = W[(size_t)(k0 + ty + r * 8) * N + n0 + tx];
        __syncthreads();
        #pragma unroll
        for (int r = 0; r < 4; ++r) {
            const int nl = ty + r * 8;
            const int nn = n0 + nl;
            int nw = nn;
            if (isQ) {
                nw = (nn & ~1023) | (((nn & 63) >> 3) << 7)
                   | (((nn >> 6) & 15) << 3) | (nn & 7);
            }
            const float v = t[tx][nl];
            const unsigned short h = f32_bf16(v);
            th[(size_t)nw * 1024 + k0 + tx] = h;
            tl[(size_t)nw * 1024 + k0 + tx] = f32_bf16(v - bf16_f32(h));
            float s = v * v;
            #pragma unroll
            for (int m = 16; m > 0; m >>= 1) s += __shfl_xor(s, m, 32);
            if (tx == 0) atomicAdd(&k2[nn], s);
        }
    } else {
        const int row = bid - 4096;
        float* red = &t[0][0];
        float4 v = *(const float4*)(x + (size_t)row * 1024 + tid * 4);
        float vv[4] = {v.x, v.y, v.z, v.w};
        unsigned short hh[4], ll[4];
        float s = 0.0f;
        #pragma unroll
        for (int e = 0; e < 4; ++e) {
            hh[e] = f32_bf16(vv[e]);
            ll[e] = f32_bf16(vv[e] - bf16_f32(hh[e]));
            s = fmaf(vv[e], vv[e], s);
        }
        *(ushort4*)(xh + (size_t)row * 1024 + tid * 4) =
            make_ushort4(hh[0], hh[1], hh[2], hh[3]);
        *(ushort4*)(xl + (size_t)row * 1024 + tid * 4) =
            make_ushort4(ll[0], ll[1], ll[2], ll[3]);
        #pragma unroll
        for (int off = 32; off > 0; off >>= 1) s += __shfl_down(s, off, 64);
        if ((tid & 63) == 0) red[tid >> 6] = s;
        __syncthreads();
        if (tid == 0) x2x[row] = red[0] + red[1] + red[2] + red[3];
    }
}

// ---------------------------------------------------------------------------
// Split-bf16 MFMA YAT-dense GEMM, templated BM x BN x BK x MINW,
// single-buffered (R1: source-level double-buffering regressed 2.4x — do
// not re-add).  MINW = actual blocks/CU (256-thread blocks: arg == k),
// frees the VGPR budget from the default high-occupancy target.
// 4 waves in a 2x2 grid, each owning a (BM/2)x(BN/2) sub-tile.
// MODE 0: row-major fp32 store.
// MODE 2: QKV (BN=128 required) — B is the PERMUTED Wt; epilogue packs
//         Q/K/V bf16 hi/lo into kvu + q2k/k2k via LDS transpose, in
//         BM/32 row-groups.
// ---------------------------------------------------------------------------
template <int BM, int BN, int BK, int MODE, int MINW>
__global__ __launch_bounds__(256, MINW) void gemm_yat_mfma_kernel(
    const unsigned short* __restrict__ Ah, const unsigned short* __restrict__ Al,
    const unsigned short* __restrict__ Bh, const unsigned short* __restrict__ Bl,
    const float* __restrict__ bias, const float* __restrict__ x2,
    const float* __restrict__ k2, const float* __restrict__ alphap,
    float* __restrict__ out, int N, int K, float scale_base,
    unsigned short* __restrict__ kvu, float* __restrict__ q2k,
    float* __restrict__ k2k)
{
    constexpr int TM = (BM / 2) / 16;
    constexpr int TN = (BN / 2) / 16;
    constexpr int ASZ = BM * BK;             // u16 per A region (hi or lo)
    constexpr int BSZ = BN * BK;             // u16 per B region
    constexpr int AB  = ASZ * 2;             // bytes per A region (pow2)
    constexpr int BB  = BSZ * 2;             // bytes per B region (pow2)
    constexpr int NI  = (BM + BN) * BK / 1024;   // global_load_lds per thread
    constexpr int LPR = BK / 8;              // lanes per staged row
    __shared__ __align__(16) unsigned short sbuf[2 * (ASZ + BSZ)];

    const int tid = threadIdx.x;
    const int w = tid >> 6, l = tid & 63;
    const int lane16 = l & 15, quad = l >> 4;
    const int wm = w & 1, wn = w >> 1;
    const int m0 = blockIdx.y * BM, n0 = blockIdx.x * BN;

    floatx4 acc[TM][TN];
    #pragma unroll
    for (int tm = 0; tm < TM; ++tm)
        #pragma unroll
        for (int tn = 0; tn < TN; ++tn)
            acc[tm][tn] = (floatx4){0.f, 0.f, 0.f, 0.f};

    for (int k0 = 0; k0 < K; k0 += BK) {
        __syncthreads();
        #pragma unroll
        for (int i = 0; i < NI; ++i) {
            const int o = (i * 4 + w) * 1024;    // byte offset in LDS
            const unsigned short* gp;
            if (o < 2 * AB) {
                const unsigned short* g = (o < AB) ? Ah : Al;
                const int oo = o & (AB - 1);
                gp = g + (size_t)(m0 + oo / (BK * 2) + l / LPR) * K
                       + k0 + (l % LPR) * 8;
            } else {
                const int ob = o - 2 * AB;
                const unsigned short* g = (ob < BB) ? Bh : Bl;
                const int oo = ob & (BB - 1);
                gp = g + (size_t)(n0 + oo / (BK * 2) + l / LPR) * K
                       + k0 + (l % LPR) * 8;
            }
            __builtin_amdgcn_global_load_lds(
                (const __attribute__((address_space(1))) unsigned int*)gp,
                (__attribute__((address_space(3))) unsigned int*)((char*)sbuf + o),
                16, 0, 0);
        }
        __syncthreads();

        #pragma unroll
        for (int kk = 0; kk < BK / 32; ++kk) {
            bf16x8 afh[TM], afl[TM], bfh[TN], bfl[TN];
            #pragma unroll
            for (int tm = 0; tm < TM; ++tm) {
                const int base = (wm * (BM / 2) + tm * 16 + lane16) * BK
                               + kk * 32 + quad * 8;
                afh[tm] = *(const bf16x8*)(sbuf + base);
                afl[tm] = *(const bf16x8*)(sbuf + ASZ + base);
            }
            #pragma unroll
            for (int tn = 0; tn < TN; ++tn) {
                const int nb = (wn * (BN / 2) + tn * 16 + lane16) * BK
                             + kk * 32 + quad * 8;
                bfh[tn] = *(const bf16x8*)(sbuf + 2 * ASZ + nb);
                bfl[tn] = *(const bf16x8*)(sbuf + 2 * ASZ + BSZ + nb);
            }
            #pragma unroll
            for (int tm = 0; tm < TM; ++tm)
                #pragma unroll
                for (int tn = 0; tn < TN; ++tn) {
                    acc[tm][tn] = __builtin_amdgcn_mfma_f32_16x16x32_bf16(
                        afh[tm], bfh[tn], acc[tm][tn], 0, 0, 0);
                    acc[tm][tn] = __builtin_amdgcn_mfma_f32_16x16x32_bf16(
                        afh[tm], bfl[tn], acc[tm][tn], 0, 0, 0);
                    acc[tm][tn] = __builtin_amdgcn_mfma_f32_16x16x32_bf16(
                        afl[tm], bfh[tn], acc[tm][tn], 0, 0, 0);
                }
        }
    }

    const float scale = powf(scale_base, alphap[0]);

    if (MODE == 0) {
        #pragma unroll
        for (int tm = 0; tm < TM; ++tm) {
            #pragma unroll
            for (int tn = 0; tn < TN; ++tn) {
                const int n = n0 + wn * (BN / 2) + tn * 16 + lane16;
                const float kk = k2[n];
                const float bb = bias[n];
                const int mrow = m0 + wm * (BM / 2) + tm * 16 + quad * 4;
                #pragma unroll
                for (int r = 0; r < 4; ++r) {
                    const float y = acc[tm][tn][r];
                    const float den = x2[mrow + r] + kk - 2.0f * y + YAT_EPS;
                    out[(size_t)(mrow + r) * N + n] =
                        y * y / den * scale + bb;
                }
            }
        }
    } else {
        // -------- MODE 2: pack epilogue (BN = 128), BM/32 row-groups --------
        constexpr int G = BM / 32;          // 32-row groups
        float* lds = (float*)sbuf;          // 32 x 132 fp32 (16.9 KB)
        const int s_ = n0 >> 10;            // 0=Q 1=K 2=V (block-const)
        const int dblk = (n0 >> 7) & 7;
        const int b_ = m0 >> 10;
        const int tl = tid >> 3;            // 0..31
        const int ddr = tid & 7;            // 0..7
        const int d_glob = dblk * 8 + ddr;

        #pragma unroll
        for (int g = 0; g < G; ++g) {
            __syncthreads();                // also covers K-loop WAR
            if constexpr (G == 1) {
                #pragma unroll
                for (int tn = 0; tn < TN; ++tn) {
                    const int n = n0 + wn * (BN / 2) + tn * 16 + lane16;
                    const int hcol = (n >> 3) & 15;
                    const int norig = (n & ~1023) | (hcol << 6)
                                    | (dblk << 3) | (n & 7);
                    const float kk = k2[norig];
                    const float bb = bias[norig];
                    const int mrow = m0 + wm * 16 + quad * 4;
                    const int tbase = wm * 16 + quad * 4;
                    const int col = wn * (BN / 2) + tn * 16 + lane16;
                    #pragma unroll
                    for (int r = 0; r < 4; ++r) {
                        const float y = acc[0][tn][r];
                        const float den =
                            x2[mrow + r] + kk - 2.0f * y + YAT_EPS;
                        lds[(tbase + r) * 132 + col] =
                            y * y / den * scale + bb;
                    }
                }
            } else {
                constexpr int GH = (G > 1) ? (G / 2) : 1;
                if (wm == g / GH) {
                    const int gl = g % GH;
                    #pragma unroll
                    for (int tm2 = 0; tm2 < 2; ++tm2) {
                        const int tm = gl * 2 + tm2;
                        #pragma unroll
                        for (int tn = 0; tn < TN; ++tn) {
                            const int n = n0 + wn * (BN / 2) + tn * 16 + lane16;
                            const int hcol = (n >> 3) & 15;
                            const int norig = (n & ~1023) | (hcol << 6)
                                            | (dblk << 3) | (n & 7);
                            const float kk = k2[norig];
                            const float bb = bias[norig];
                            const int mrow =
                                m0 + wm * (BM / 2) + tm * 16 + quad * 4;
                            const int tbase = tm2 * 16 + quad * 4;
                            const int col = wn * (BN / 2) + tn * 16 + lane16;
                            #pragma unroll
                            for (int r = 0; r < 4; ++r) {
                                const float y = acc[tm][tn][r];
                                const float den =
                                    x2[mrow + r] + kk - 2.0f * y + YAT_EPS;
                                lds[(tbase + r) * 132 + col] =
                                    y * y / den * scale + bb;
                            }
                        }
                    }
                }
            }
            __syncthreads();

            float y[16];
            #pragma unroll
            for (int h = 0; h < 16; ++h)
                y[h] = lds[tl * 132 + h * 8 + ddr];
            const int t_glob = (m0 & 1023) + g * 32 + tl;

            if (s_ < 2) {
                unsigned short hb[16], lb[16];
                float s2 = 0.f;
                #pragma unroll
                for (int h = 0; h < 16; ++h) {
                    hb[h] = f32_bf16(y[h]);
                    lb[h] = f32_bf16(y[h] - bf16_f32(hb[h]));
                    s2 = fmaf(y[h], y[h], s2);
                }
                unsigned short* dst = kvu + (size_t)b_ * 6291456
                    + (s_ == 0 ? 4194304u : 0u)
                    + ((size_t)(d_glob * 1024 + t_glob)) * 32;
                #pragma unroll
                for (int h4 = 0; h4 < 4; ++h4) {
                    *(ushort4*)(dst + h4 * 4) = make_ushort4(
                        hb[h4*4], hb[h4*4+1], hb[h4*4+2], hb[h4*4+3]);
                    *(ushort4*)(dst + 16 + h4 * 4) = make_ushort4(
                        lb[h4*4], lb[h4*4+1], lb[h4*4+2], lb[h4*4+3]);
                }
                float* sq = (s_ == 0) ? q2k : k2k;
                sq[b_ * 65536 + d_glob * 1024 + t_glob] = s2;
            } else {
                const int j = t_glob;
                const int jt2 = j >> 5;
                const int e = ((j >> 4) & 1) * 4 + (j & 3);
                const int qd = (j >> 2) & 3;
                unsigned short* dst = kvu + (size_t)b_ * 6291456 + 2097152
                    + d_glob * 32768 + jt2 * 1024 + qd * 128 + e;
                #pragma unroll
                for (int h = 0; h < 16; ++h) {
                    const unsigned short vh = f32_bf16(y[h]);
                    dst[h * 8] = vh;
                    dst[512 + h * 8] = f32_bf16(y[h] - bf16_f32(vh));
                }
            }
        }
    }
}

// ---------------------------------------------------------------------------
// Transpose-free MFMA flash attention (R9 structure; trunc-pack for P).
// S^T = K.Q^T leaves S with i=lane16, j=quad*4+r — the A-operand layout for
// P.V.  P packed to bf16 hi/lo in registers; zero LDS, zero barriers.
// Wave owns i-tiles (ti0, 63-ti0) in the same jt2 loop sharing K/V frags.
// launch_bounds(256,4): grid 1024 = 4 blocks/CU; VGPR cap 128 > ~100 live.
// ---------------------------------------------------------------------------
__global__ __launch_bounds__(256, 4) void yat_attn_mfma2_kernel(
    const unsigned short* __restrict__ KVU,
    const float* __restrict__ k2k, const float* __restrict__ q2k,
    const float* __restrict__ alphap,
    unsigned short* __restrict__ attn_h, unsigned short* __restrict__ attn_l,
    float* __restrict__ x2a)
{
    const int tid = threadIdx.x;
    const int lane = tid & 63, w = tid >> 6;
    const int lane16 = lane & 15, quad = lane >> 4;
    const int d = blockIdx.x, c = blockIdx.y, b = blockIdx.z;

    const float isc =
        powf(64.0f / log1pf(64.0f), alphap[0]) * 1.44269504f;  // log2 domain

    const unsigned short* kp = KVU + (size_t)b * 6291456 + d * 32768;
    const unsigned short* vp = KVU + (size_t)b * 6291456 + 2097152 + d * 32768;
    const unsigned short* qp = KVU + (size_t)b * 6291456 + 4194304 + d * 32768;
    const float* k2bd = k2k + b * 65536 + d * 1024;
    const float* q2bd = q2k + b * 65536 + d * 1024;

    const int ti0 = c * 4 + w;            // 0..31
    const int tiA = ti0, tiB = 63 - ti0;

    const bf16x8 qA = *(const bf16x8*)(qp + (tiA * 16 + lane16) * 32 + quad * 8);
    const bf16x8 qB = *(const bf16x8*)(qp + (tiB * 16 + lane16) * 32 + quad * 8);
    const float q2A = q2bd[tiA * 16 + lane16] + YAT_EPS;
    const float q2B = q2bd[tiB * 16 + lane16] + YAT_EPS;
    const int iA = tiA * 16 + lane16;
    const int iB = tiB * 16 + lane16;

    floatx4 OA = (floatx4){0.f, 0.f, 0.f, 0.f};
    floatx4 OB = (floatx4){0.f, 0.f, 0.f, 0.f};
    float lsA = 0.f, lsB = 0.f;

    const int lastA = tiA >> 1, lastB = tiB >> 1;

    for (int jt2 = 0; jt2 <= lastB; ++jt2) {
        const int j0 = jt2 * 32;
        const unsigned short* kp0 = kp + (j0 + lane16) * 32;
        const unsigned short* kp1 = kp + (j0 + 16 + lane16) * 32;
        const bf16x8 k0a = *(const bf16x8*)(kp0 + quad * 8);
        const bf16x8 k0b = *(const bf16x8*)(kp0 + ((quad ^ 2) * 8));
        const bf16x8 k1a = *(const bf16x8*)(kp1 + quad * 8);
        const bf16x8 k1b = *(const bf16x8*)(kp1 + ((quad ^ 2) * 8));
        const unsigned short* vpj = vp + jt2 * 1024 + quad * 128 + lane16 * 8;
        const bf16x8 vh = *(const bf16x8*)(vpj);
        const bf16x8 vl = *(const bf16x8*)(vpj + 512);
        const float4 k20 = *(const float4*)(k2bd + j0 + quad * 4);
        const float4 k21 = *(const float4*)(k2bd + j0 + 16 + quad * 4);
        const float k2r[8] = {k20.x, k20.y, k20.z, k20.w,
                              k21.x, k21.y, k21.z, k21.w};
        const int jbase0 = j0 + quad * 4;

        #pragma unroll
        for (int half = 0; half < 2; ++half) {
            if (half == 0 && jt2 > lastA) continue;
            const bf16x8 qf = half ? qB : qA;
            const float q2e = half ? q2B : q2A;
            const int iM = half ? iB : iA;
            floatx4 S0 = __builtin_amdgcn_mfma_f32_16x16x32_bf16(
                k0a, qf, (floatx4){0.f, 0.f, 0.f, 0.f}, 0, 0, 0);
            S0 = __builtin_amdgcn_mfma_f32_16x16x32_bf16(k0b, qf, S0, 0, 0, 0);
            floatx4 S1 = __builtin_amdgcn_mfma_f32_16x16x32_bf16(
                k1a, qf, (floatx4){0.f, 0.f, 0.f, 0.f}, 0, 0, 0);
            S1 = __builtin_amdgcn_mfma_f32_16x16x32_bf16(k1b, qf, S1, 0, 0, 0);

            float p[8], lsum = 0.f;
            #pragma unroll
            for (int e = 0; e < 8; ++e) {
                const float s = (e < 4) ? S0[e & 3] : S1[e & 3];
                const int j = jbase0 + (e >> 2) * 16 + (e & 3);
                const float den = fmaf(-2.f, s, q2e + k2r[e]);
                float pe = fast_exp2(s * s * fast_rcp(den) * isc);
                pe = (j <= iM) ? pe : 0.f;
                lsum += pe;
                p[e] = pe;
            }
            if (half) lsB += lsum; else lsA += lsum;

            // pack P -> bf16 hi (trunc) / lo (trunc of exact residual):
            // Ph+Pl ~= p to 2^-16; dropped Pl*vl term ~2^-17.
            unsigned ph32[4], pl32[4];
            #pragma unroll
            for (int e2 = 0; e2 < 4; ++e2) {
                const unsigned b0 = __builtin_bit_cast(unsigned, p[e2 * 2]);
                const unsigned b1 = __builtin_bit_cast(unsigned, p[e2 * 2 + 1]);
                ph32[e2] = (b0 >> 16) | (b1 & 0xFFFF0000u);
                const float f0 = p[e2 * 2] -
                    __builtin_bit_cast(float, b0 & 0xFFFF0000u);
                const float f1 = p[e2 * 2 + 1] -
                    __builtin_bit_cast(float, b1 & 0xFFFF0000u);
                pl32[e2] = (__builtin_bit_cast(unsigned, f0) >> 16) |
                           (__builtin_bit_cast(unsigned, f1) & 0xFFFF0000u);
            }
            const bf16x8 Ph = __builtin_bit_cast(bf16x8,
                (uintx4){ph32[0], ph32[1], ph32[2], ph32[3]});
            const bf16x8 Pl = __builtin_bit_cast(bf16x8,
                (uintx4){pl32[0], pl32[1], pl32[2], pl32[3]});

            floatx4 O = half ? OB : OA;
            O = __builtin_amdgcn_mfma_f32_16x16x32_bf16(Ph, vh, O, 0, 0, 0);
            O = __builtin_amdgcn_mfma_f32_16x16x32_bf16(Pl, vh, O, 0, 0, 0);
            O = __builtin_amdgcn_mfma_f32_16x16x32_bf16(Ph, vl, O, 0, 0, 0);
            if (half) OB = O; else OA = O;
        }
    }

    #pragma unroll
    for (int half = 0; half < 2; ++half) {
        float ls = half ? lsB : lsA;
        const floatx4 O = half ? OB : OA;
        const int ti = half ? tiB : tiA;
        ls += __shfl_xor(ls, 16, 64);
        ls += __shfl_xor(ls, 32, 64);
        const float linv = 1.0f / ls;
        #pragma unroll
        for (int r = 0; r < 4; ++r) {
            const float lr = __shfl(linv, quad * 4 + r, 16);
            const float v = O[r] * lr;
            const int i = ti * 16 + quad * 4 + r;
            const size_t off =
                ((size_t)(b * 1024 + i)) * 1024 + d * 16 + lane16;
            const unsigned short vh16 = f32_bf16(v);
            attn_h[off] = vh16;
            attn_l[off] = f32_bf16(v - bf16_f32(vh16));
            float s2 = v * v;
            s2 += __shfl_xor(s2, 1, 64);
            s2 += __shfl_xor(s2, 2, 64);
            s2 += __shfl_xor(s2, 4, 64);
            s2 += __shfl_xor(s2, 8, 64);
            if (lane16 == 0) atomicAdd(&x2a[b * 1024 + i], s2);
        }
    }
}

// ---------------------------------------------------------------------------
extern "C" void kernel_launch(void* const* d_in, const int* in_sizes, int n_in,
                              void* d_out, int out_size, void* d_ws, size_t ws_size,
                              hipStream_t stream)
{
    const float* x          = (const float*)d_in[0];
    // d_in[1] = causal mask, constant — causality hard-coded
    const float* w_qkv      = (const float*)d_in[2];
    const float* b_qkv      = (const float*)d_in[3];
    const float* alpha_qkv  = (const float*)d_in[4];
    const float* w_proj     = (const float*)d_in[5];
    const float* b_proj     = (const float*)d_in[6];
    const float* alpha_proj = (const float*)d_in[7];
    const float* alpha_attn = (const float*)d_in[8];
    float* out = (float*)d_out;

    float* ws = (float*)d_ws;
    unsigned short* KVU  = (unsigned short*)ws;                  // 6291456 f region
    unsigned short* WtQh = (unsigned short*)(ws + 6291456);      // 3072x1024 bf16 (permuted)
    unsigned short* WtQl = (unsigned short*)(ws + 7864320);
    unsigned short* WtPh = (unsigned short*)(ws + 9437184);      // 1024x1024 bf16
    unsigned short* WtPl = (unsigned short*)(ws + 9961472);
    unsigned short* xh   = (unsigned short*)(ws + 10485760);     // 2048x1024 bf16
    unsigned short* xl   = (unsigned short*)(ws + 11534336);
    float* x2x  = ws + 12582912;   // 2048
    float* x2a  = ws + 12584960;   // 2048 (atomic)
    float* k2q  = ws + 12587008;   // 3072 (atomic)
    float* k2p  = ws + 12590080;   // 1024 (atomic)
    float* k2k  = ws + 12591104;   // 131072
    float* q2k  = ws + 12722176;   // 131072   (total 12853248 f = 51.4 MB)
    unsigned short* attn_h = WtQh;             // WtQ dead after QKV GEMM
    unsigned short* attn_l = WtQl;

    // zero atomic accumulators (x2a, k2q, k2p contiguous)
    hipMemsetAsync(x2a, 0, (2048 + 3072 + 1024) * sizeof(float), stream);

    // one merged prep dispatch: both weight transposes + x conversion
    prep_kernel<<<6144, 256, 0, stream>>>(
        x, w_qkv, w_proj, xh, xl, x2x, WtQh, WtQl, k2q, WtPh, WtPl, k2p);

    // QKV GEMM + fused Q/K/V pack (writes KVU, q2k, k2k directly)
    // 64x128 BK=64, minw=3 (LDS 48KB -> 3 blocks/CU; VGPR cap ~170)
    const float sb_qkv = sqrtf(3072.0f) / log1pf(3072.0f);
    gemm_yat_mfma_kernel<64, 128, 64, 2, 3><<<dim3(24, 32), 256, 0, stream>>>(
        xh, xl, WtQh, WtQl, b_qkv, x2x, k2q, alpha_qkv, nullptr,
        3072, 1024, sb_qkv, KVU, q2k, k2k);

    yat_attn_mfma2_kernel<<<dim3(64, 8, 2), 256, 0, stream>>>(
        KVU, k2k, q2k, alpha_attn, attn_h, attn_l, x2a);

    // proj: 64x64 BK=64, minw=2 (grid 512 = 2 blocks/CU; VGPR cap 256)
    const float sb_proj = sqrtf(1024.0f) / log1pf(1024.0f);
    gemm_yat_mfma_kernel<64, 64, 64, 0, 2><<<dim3(16, 32), 256, 0, stream>>>(
        attn_h, attn_l, WtPh, WtPl, b_proj, x2a, k2p, alpha_proj, out,
        1024, 1024, sb_proj, nullptr, nullptr, nullptr);
}

// Round 6
// 219.919 us; speedup vs baseline: 1.1758x; 1.0335x over previous
//
#include <hip/hip_runtime.h>
#include <math.h>

#define YAT_EPS (1.0f / 137.0f)

// Logical sizes (fixed): B=2, T=1024, C=1024.
// Attention (faithful to reference transpose): 64 "heads" (d axis),
// per-head dim 16 (h axis), causal, T=1024.
//
// Packed KV region, per b (stride 6291456 u16):
//   KP at +0        : [d][t][kh16|kl16]            (2097152 u16)
//   VP at +2097152  : [d][jt2][hl][quad][h][e]     (2097152 u16)
//   QP at +4194304  : [d][t][qh16|ql16]            (2097152 u16)
//
// GEMM experiment history (keep — these triangulate the model):
//   R1: 2-phase dbuf @64x128      -> 153us  (codegen collapse; NO source
//       pipelining grafts on this structure)
//   R2: 128x128 (1.5 blk/CU)      -> 70us
//   R0: 64x128  (3 blk/CU) BK=32  -> 63.5us
//   R3: 32x128  (6 blk/CU)        -> 92us   (2x B-staging; TLP not the fix)
//   R4: 64x128 BK=64              -> 63.5us (barriers halved: no change;
//       conflicts 3x'd: no change — both off critical path)
//   R5: launch_bounds minw        -> 63.5us, VGPR stayed 68 (not reg-bound)
//   => QKV CLOSED at 63.5us / 610 TF (5 invariant experiments). Remaining
//      163.8us is prep+attn+proj+dispatch overhead (none in top-5).
//   R6: attn fast-path + setprio + v_perm pack; prep ushort2 stores;
//       x2a zero folded into prep. If total moves <2us -> overhead
//       dominates -> R7 cooperative fusion.

typedef __bf16 bf16x8 __attribute__((ext_vector_type(8)));
typedef float floatx4 __attribute__((ext_vector_type(4)));
typedef unsigned int uintx4 __attribute__((ext_vector_type(4)));

__device__ __forceinline__ float fast_rcp(float x) {
#if __has_builtin(__builtin_amdgcn_rcpf)
    return __builtin_amdgcn_rcpf(x);
#else
    return 1.0f / x;
#endif
}
__device__ __forceinline__ float fast_exp2(float x) {
#if __has_builtin(__builtin_amdgcn_exp2f)
    return __builtin_amdgcn_exp2f(x);
#else
    return exp2f(x);
#endif
}

__device__ __forceinline__ unsigned short f32_bf16(float f) {
    unsigned u = __builtin_bit_cast(unsigned, f);
    u += 0x7fffu + ((u >> 16) & 1u);      // RNE; inputs are finite/normal
    return (unsigned short)(u >> 16);
}
__device__ __forceinline__ float bf16_f32(unsigned short h) {
    unsigned u = ((unsigned)h) << 16;
    return __builtin_bit_cast(float, u);
}

// ---------------------------------------------------------------------------
// Merged prep: one dispatch, three block-range sections (K=1024 throughout).
//  bid <  3072 : w_qkv -> WtQh/WtQl (PERMUTED rows) + k2q (atomic)
//  bid <  4096 : w_proj -> WtPh/WtPl + k2p (atomic)
//  bid >= 4096 : x row -> xh/xl bf16 hi/lo + x2x[row] (+ zero x2a[row])
// Permutation (qkv only): n' = s*1024 + (d>>3)*128 + h*8 + (d&7) so a GEMM
// n-block covers (one s, all 16 h, 8 d) — required by the pack epilogue.
// R6: transpose stores vectorized to ushort2 (each thread handles 2 k).
// ---------------------------------------------------------------------------
__global__ __launch_bounds__(256) void prep_kernel(
    const float* __restrict__ x,
    const float* __restrict__ w_qkv, const float* __restrict__ w_proj,
    unsigned short* __restrict__ xh, unsigned short* __restrict__ xl,
    float* __restrict__ x2x,
    unsigned short* __restrict__ WtQh, unsigned short* __restrict__ WtQl,
    float* __restrict__ k2q,
    unsigned short* __restrict__ WtPh, unsigned short* __restrict__ WtPl,
    float* __restrict__ k2p,
    float* __restrict__ x2a)
{
    __shared__ float t[32][33];
    const int bid = blockIdx.x;
    const int tid = threadIdx.x;

    if (bid < 4096) {
        const bool isQ = bid < 3072;
        const float* W = isQ ? w_qkv : w_proj;
        unsigned short* th = isQ ? WtQh : WtPh;
        unsigned short* tl = isQ ? WtQl : WtPl;
        float* k2 = isQ ? k2q : k2p;
        const int N = isQ ? 3072 : 1024;
        const int id2 = isQ ? bid : bid - 3072;
        const int nx = isQ ? (id2 % 96) : (id2 & 31);
        const int ky = isQ ? (id2 / 96) : (id2 >> 5);
        const int tx = tid & 31, ty = tid >> 5;
        const int n0 = nx * 32, k0 = ky * 32;
        #pragma unroll
        for (int r = 0; r < 4; ++r)
            t[ty + r * 8][tx] = W[(size_t)(k0 + ty + r * 8) * N + n0 + tx];
        __syncthreads();
        // vectorized transpose-store: 16 k-pairs x 16 n-rows, 2 passes
        const int tx2 = tid & 15, ty2 = tid >> 4;
        #pragma unroll
        for (int r = 0; r < 2; ++r) {
            const int nl = ty2 + r * 16;
            const int nn = n0 + nl;
            int nw = nn;
            if (isQ) {
                nw = (nn & ~1023) | (((nn & 63) >> 3) << 7)
                   | (((nn >> 6) & 15) << 3) | (nn & 7);
            }
            const float v0 = t[2 * tx2][nl];
            const float v1 = t[2 * tx2 + 1][nl];
            const unsigned short h0 = f32_bf16(v0);
            const unsigned short h1 = f32_bf16(v1);
            *(ushort2*)(th + (size_t)nw * 1024 + k0 + 2 * tx2) =
                make_ushort2(h0, h1);
            *(ushort2*)(tl + (size_t)nw * 1024 + k0 + 2 * tx2) =
                make_ushort2(f32_bf16(v0 - bf16_f32(h0)),
                             f32_bf16(v1 - bf16_f32(h1)));
            float s = fmaf(v0, v0, v1 * v1);
            #pragma unroll
            for (int m = 8; m > 0; m >>= 1) s += __shfl_xor(s, m, 16);
            if (tx2 == 0) atomicAdd(&k2[nn], s);
        }
    } else {
        const int row = bid - 4096;
        float* red = &t[0][0];
        float4 v = *(const float4*)(x + (size_t)row * 1024 + tid * 4);
        float vv[4] = {v.x, v.y, v.z, v.w};
        unsigned short hh[4], ll[4];
        float s = 0.0f;
        #pragma unroll
        for (int e = 0; e < 4; ++e) {
            hh[e] = f32_bf16(vv[e]);
            ll[e] = f32_bf16(vv[e] - bf16_f32(hh[e]));
            s = fmaf(vv[e], vv[e], s);
        }
        *(ushort4*)(xh + (size_t)row * 1024 + tid * 4) =
            make_ushort4(hh[0], hh[1], hh[2], hh[3]);
        *(ushort4*)(xl + (size_t)row * 1024 + tid * 4) =
            make_ushort4(ll[0], ll[1], ll[2], ll[3]);
        #pragma unroll
        for (int off = 32; off > 0; off >>= 1) s += __shfl_down(s, off, 64);
        if ((tid & 63) == 0) red[tid >> 6] = s;
        __syncthreads();
        if (tid == 0) {
            x2x[row] = red[0] + red[1] + red[2] + red[3];
            x2a[row] = 0.0f;            // attn's atomic accumulator (runs 2
        }                               // dispatches later — safe to zero here)
    }
}

// ---------------------------------------------------------------------------
// Split-bf16 MFMA YAT-dense GEMM, templated BM x BN x BK x MINW,
// single-buffered (R1: source-level double-buffering regressed 2.4x — do
// not re-add).  CLOSED at 63.5us for QKV (see history above).
// 4 waves in a 2x2 grid, each owning a (BM/2)x(BN/2) sub-tile.
// MODE 0: row-major fp32 store.
// MODE 2: QKV (BN=128 required) — B is the PERMUTED Wt; epilogue packs
//         Q/K/V bf16 hi/lo into kvu + q2k/k2k via LDS transpose, in
//         BM/32 row-groups.
// ---------------------------------------------------------------------------
template <int BM, int BN, int BK, int MODE, int MINW>
__global__ __launch_bounds__(256, MINW) void gemm_yat_mfma_kernel(
    const unsigned short* __restrict__ Ah, const unsigned short* __restrict__ Al,
    const unsigned short* __restrict__ Bh, const unsigned short* __restrict__ Bl,
    const float* __restrict__ bias, const float* __restrict__ x2,
    const float* __restrict__ k2, const float* __restrict__ alphap,
    float* __restrict__ out, int N, int K, float scale_base,
    unsigned short* __restrict__ kvu, float* __restrict__ q2k,
    float* __restrict__ k2k)
{
    constexpr int TM = (BM / 2) / 16;
    constexpr int TN = (BN / 2) / 16;
    constexpr int ASZ = BM * BK;             // u16 per A region (hi or lo)
    constexpr int BSZ = BN * BK;             // u16 per B region
    constexpr int AB  = ASZ * 2;             // bytes per A region (pow2)
    constexpr int BB  = BSZ * 2;             // bytes per B region (pow2)
    constexpr int NI  = (BM + BN) * BK / 1024;   // global_load_lds per thread
    constexpr int LPR = BK / 8;              // lanes per staged row
    __shared__ __align__(16) unsigned short sbuf[2 * (ASZ + BSZ)];

    const int tid = threadIdx.x;
    const int w = tid >> 6, l = tid & 63;
    const int lane16 = l & 15, quad = l >> 4;
    const int wm = w & 1, wn = w >> 1;
    const int m0 = blockIdx.y * BM, n0 = blockIdx.x * BN;

    floatx4 acc[TM][TN];
    #pragma unroll
    for (int tm = 0; tm < TM; ++tm)
        #pragma unroll
        for (int tn = 0; tn < TN; ++tn)
            acc[tm][tn] = (floatx4){0.f, 0.f, 0.f, 0.f};

    for (int k0 = 0; k0 < K; k0 += BK) {
        __syncthreads();
        #pragma unroll
        for (int i = 0; i < NI; ++i) {
            const int o = (i * 4 + w) * 1024;    // byte offset in LDS
            const unsigned short* gp;
            if (o < 2 * AB) {
                const unsigned short* g = (o < AB) ? Ah : Al;
                const int oo = o & (AB - 1);
                gp = g + (size_t)(m0 + oo / (BK * 2) + l / LPR) * K
                       + k0 + (l % LPR) * 8;
            } else {
                const int ob = o - 2 * AB;
                const unsigned short* g = (ob < BB) ? Bh : Bl;
                const int oo = ob & (BB - 1);
                gp = g + (size_t)(n0 + oo / (BK * 2) + l / LPR) * K
                       + k0 + (l % LPR) * 8;
            }
            __builtin_amdgcn_global_load_lds(
                (const __attribute__((address_space(1))) unsigned int*)gp,
                (__attribute__((address_space(3))) unsigned int*)((char*)sbuf + o),
                16, 0, 0);
        }
        __syncthreads();

        #pragma unroll
        for (int kk = 0; kk < BK / 32; ++kk) {
            bf16x8 afh[TM], afl[TM], bfh[TN], bfl[TN];
            #pragma unroll
            for (int tm = 0; tm < TM; ++tm) {
                const int base = (wm * (BM / 2) + tm * 16 + lane16) * BK
                               + kk * 32 + quad * 8;
                afh[tm] = *(const bf16x8*)(sbuf + base);
                afl[tm] = *(const bf16x8*)(sbuf + ASZ + base);
            }
            #pragma unroll
            for (int tn = 0; tn < TN; ++tn) {
                const int nb = (wn * (BN / 2) + tn * 16 + lane16) * BK
                             + kk * 32 + quad * 8;
                bfh[tn] = *(const bf16x8*)(sbuf + 2 * ASZ + nb);
                bfl[tn] = *(const bf16x8*)(sbuf + 2 * ASZ + BSZ + nb);
            }
            #pragma unroll
            for (int tm = 0; tm < TM; ++tm)
                #pragma unroll
                for (int tn = 0; tn < TN; ++tn) {
                    acc[tm][tn] = __builtin_amdgcn_mfma_f32_16x16x32_bf16(
                        afh[tm], bfh[tn], acc[tm][tn], 0, 0, 0);
                    acc[tm][tn] = __builtin_amdgcn_mfma_f32_16x16x32_bf16(
                        afh[tm], bfl[tn], acc[tm][tn], 0, 0, 0);
                    acc[tm][tn] = __builtin_amdgcn_mfma_f32_16x16x32_bf16(
                        afl[tm], bfh[tn], acc[tm][tn], 0, 0, 0);
                }
        }
    }

    const float scale = powf(scale_base, alphap[0]);

    if (MODE == 0) {
        #pragma unroll
        for (int tm = 0; tm < TM; ++tm) {
            #pragma unroll
            for (int tn = 0; tn < TN; ++tn) {
                const int n = n0 + wn * (BN / 2) + tn * 16 + lane16;
                const float kk = k2[n];
                const float bb = bias[n];
                const int mrow = m0 + wm * (BM / 2) + tm * 16 + quad * 4;
                #pragma unroll
                for (int r = 0; r < 4; ++r) {
                    const float y = acc[tm][tn][r];
                    const float den = x2[mrow + r] + kk - 2.0f * y + YAT_EPS;
                    out[(size_t)(mrow + r) * N + n] =
                        y * y / den * scale + bb;
                }
            }
        }
    } else {
        // -------- MODE 2: pack epilogue (BN = 128), BM/32 row-groups --------
        constexpr int G = BM / 32;          // 32-row groups
        float* lds = (float*)sbuf;          // 32 x 132 fp32 (16.9 KB)
        const int s_ = n0 >> 10;            // 0=Q 1=K 2=V (block-const)
        const int dblk = (n0 >> 7) & 7;
        const int b_ = m0 >> 10;
        const int tl = tid >> 3;            // 0..31
        const int ddr = tid & 7;            // 0..7
        const int d_glob = dblk * 8 + ddr;

        #pragma unroll
        for (int g = 0; g < G; ++g) {
            __syncthreads();                // also covers K-loop WAR
            if constexpr (G == 1) {
                #pragma unroll
                for (int tn = 0; tn < TN; ++tn) {
                    const int n = n0 + wn * (BN / 2) + tn * 16 + lane16;
                    const int hcol = (n >> 3) & 15;
                    const int norig = (n & ~1023) | (hcol << 6)
                                    | (dblk << 3) | (n & 7);
                    const float kk = k2[norig];
                    const float bb = bias[norig];
                    const int mrow = m0 + wm * 16 + quad * 4;
                    const int tbase = wm * 16 + quad * 4;
                    const int col = wn * (BN / 2) + tn * 16 + lane16;
                    #pragma unroll
                    for (int r = 0; r < 4; ++r) {
                        const float y = acc[0][tn][r];
                        const float den =
                            x2[mrow + r] + kk - 2.0f * y + YAT_EPS;
                        lds[(tbase + r) * 132 + col] =
                            y * y / den * scale + bb;
                    }
                }
            } else {
                constexpr int GH = (G > 1) ? (G / 2) : 1;
                if (wm == g / GH) {
                    const int gl = g % GH;
                    #pragma unroll
                    for (int tm2 = 0; tm2 < 2; ++tm2) {
                        const int tm = gl * 2 + tm2;
                        #pragma unroll
                        for (int tn = 0; tn < TN; ++tn) {
                            const int n = n0 + wn * (BN / 2) + tn * 16 + lane16;
                            const int hcol = (n >> 3) & 15;
                            const int norig = (n & ~1023) | (hcol << 6)
                                            | (dblk << 3) | (n & 7);
                            const float kk = k2[norig];
                            const float bb = bias[norig];
                            const int mrow =
                                m0 + wm * (BM / 2) + tm * 16 + quad * 4;
                            const int tbase = tm2 * 16 + quad * 4;
                            const int col = wn * (BN / 2) + tn * 16 + lane16;
                            #pragma unroll
                            for (int r = 0; r < 4; ++r) {
                                const float y = acc[tm][tn][r];
                                const float den =
                                    x2[mrow + r] + kk - 2.0f * y + YAT_EPS;
                                lds[(tbase + r) * 132 + col] =
                                    y * y / den * scale + bb;
                            }
                        }
                    }
                }
            }
            __syncthreads();

            float y[16];
            #pragma unroll
            for (int h = 0; h < 16; ++h)
                y[h] = lds[tl * 132 + h * 8 + ddr];
            const int t_glob = (m0 & 1023) + g * 32 + tl;

            if (s_ < 2) {
                unsigned short hb[16], lb[16];
                float s2 = 0.f;
                #pragma unroll
                for (int h = 0; h < 16; ++h) {
                    hb[h] = f32_bf16(y[h]);
                    lb[h] = f32_bf16(y[h] - bf16_f32(hb[h]));
                    s2 = fmaf(y[h], y[h], s2);
                }
                unsigned short* dst = kvu + (size_t)b_ * 6291456
                    + (s_ == 0 ? 4194304u : 0u)
                    + ((size_t)(d_glob * 1024 + t_glob)) * 32;
                #pragma unroll
                for (int h4 = 0; h4 < 4; ++h4) {
                    *(ushort4*)(dst + h4 * 4) = make_ushort4(
                        hb[h4*4], hb[h4*4+1], hb[h4*4+2], hb[h4*4+3]);
                    *(ushort4*)(dst + 16 + h4 * 4) = make_ushort4(
                        lb[h4*4], lb[h4*4+1], lb[h4*4+2], lb[h4*4+3]);
                }
                float* sq = (s_ == 0) ? q2k : k2k;
                sq[b_ * 65536 + d_glob * 1024 + t_glob] = s2;
            } else {
                const int j = t_glob;
                const int jt2 = j >> 5;
                const int e = ((j >> 4) & 1) * 4 + (j & 3);
                const int qd = (j >> 2) & 3;
                unsigned short* dst = kvu + (size_t)b_ * 6291456 + 2097152
                    + d_glob * 32768 + jt2 * 1024 + qd * 128 + e;
                #pragma unroll
                for (int h = 0; h < 16; ++h) {
                    const unsigned short vh = f32_bf16(y[h]);
                    dst[h * 8] = vh;
                    dst[512 + h * 8] = f32_bf16(y[h] - bf16_f32(vh));
                }
            }
        }
    }
}

// ---------------------------------------------------------------------------
// Transpose-free MFMA flash attention (R9 structure; trunc-pack for P).
// S^T = K.Q^T leaves S with i=lane16, j=quad*4+r — the A-operand layout for
// P.V.  P packed to bf16 hi/lo in registers; zero LDS, zero barriers.
// Wave owns i-tiles (ti0, 63-ti0) in the same jt2 loop sharing K/V frags.
// R6: (a) wave-uniform full-tile fast path skips causal-mask VALU (~85% of
// tiles); (b) setprio(1) around MFMA clusters (T5; m191 regime: independent
// barrier-free waves); (c) v_perm_b32 pack.
// ---------------------------------------------------------------------------
__global__ __launch_bounds__(256, 4) void yat_attn_mfma2_kernel(
    const unsigned short* __restrict__ KVU,
    const float* __restrict__ k2k, const float* __restrict__ q2k,
    const float* __restrict__ alphap,
    unsigned short* __restrict__ attn_h, unsigned short* __restrict__ attn_l,
    float* __restrict__ x2a)
{
    const int tid = threadIdx.x;
    const int lane = tid & 63, w = tid >> 6;
    const int lane16 = lane & 15, quad = lane >> 4;
    const int d = blockIdx.x, c = blockIdx.y, b = blockIdx.z;

    const float isc =
        powf(64.0f / log1pf(64.0f), alphap[0]) * 1.44269504f;  // log2 domain

    const unsigned short* kp = KVU + (size_t)b * 6291456 + d * 32768;
    const unsigned short* vp = KVU + (size_t)b * 6291456 + 2097152 + d * 32768;
    const unsigned short* qp = KVU + (size_t)b * 6291456 + 4194304 + d * 32768;
    const float* k2bd = k2k + b * 65536 + d * 1024;
    const float* q2bd = q2k + b * 65536 + d * 1024;

    const int ti0 = c * 4 + w;            // 0..31
    const int tiA = ti0, tiB = 63 - ti0;

    const bf16x8 qA = *(const bf16x8*)(qp + (tiA * 16 + lane16) * 32 + quad * 8);
    const bf16x8 qB = *(const bf16x8*)(qp + (tiB * 16 + lane16) * 32 + quad * 8);
    const float q2A = q2bd[tiA * 16 + lane16] + YAT_EPS;
    const float q2B = q2bd[tiB * 16 + lane16] + YAT_EPS;
    const int iA = tiA * 16 + lane16;
    const int iB = tiB * 16 + lane16;

    floatx4 OA = (floatx4){0.f, 0.f, 0.f, 0.f};
    floatx4 OB = (floatx4){0.f, 0.f, 0.f, 0.f};
    float lsA = 0.f, lsB = 0.f;

    const int lastA = tiA >> 1, lastB = tiB >> 1;

    for (int jt2 = 0; jt2 <= lastB; ++jt2) {
        const int j0 = jt2 * 32;
        const unsigned short* kp0 = kp + (j0 + lane16) * 32;
        const unsigned short* kp1 = kp + (j0 + 16 + lane16) * 32;
        const bf16x8 k0a = *(const bf16x8*)(kp0 + quad * 8);
        const bf16x8 k0b = *(const bf16x8*)(kp0 + ((quad ^ 2) * 8));
        const bf16x8 k1a = *(const bf16x8*)(kp1 + quad * 8);
        const bf16x8 k1b = *(const bf16x8*)(kp1 + ((quad ^ 2) * 8));
        const unsigned short* vpj = vp + jt2 * 1024 + quad * 128 + lane16 * 8;
        const bf16x8 vh = *(const bf16x8*)(vpj);
        const bf16x8 vl = *(const bf16x8*)(vpj + 512);
        const float4 k20 = *(const float4*)(k2bd + j0 + quad * 4);
        const float4 k21 = *(const float4*)(k2bd + j0 + 16 + quad * 4);
        const float k2r[8] = {k20.x, k20.y, k20.z, k20.w,
                              k21.x, k21.y, k21.z, k21.w};
        const int jbase0 = j0 + quad * 4;

        #pragma unroll
        for (int half = 0; half < 2; ++half) {
            if (half == 0 && jt2 > lastA) continue;
            const bf16x8 qf = half ? qB : qA;
            const float q2e = half ? q2B : q2A;
            const int iM = half ? iB : iA;
            const int tiH = half ? tiB : tiA;

            __builtin_amdgcn_s_setprio(1);
            floatx4 S0 = __builtin_amdgcn_mfma_f32_16x16x32_bf16(
                k0a, qf, (floatx4){0.f, 0.f, 0.f, 0.f}, 0, 0, 0);
            S0 = __builtin_amdgcn_mfma_f32_16x16x32_bf16(k0b, qf, S0, 0, 0, 0);
            floatx4 S1 = __builtin_amdgcn_mfma_f32_16x16x32_bf16(
                k1a, qf, (floatx4){0.f, 0.f, 0.f, 0.f}, 0, 0, 0);
            S1 = __builtin_amdgcn_mfma_f32_16x16x32_bf16(k1b, qf, S1, 0, 0, 0);
            __builtin_amdgcn_s_setprio(0);

            float p[8], lsum = 0.f;
            // wave-uniform: tile fully below diagonal (min_i = tiH*16) -> no
            // mask / j-index VALU needed. ~85-90% of tiles take this path.
            if (j0 + 31 <= tiH * 16) {
                #pragma unroll
                for (int e = 0; e < 8; ++e) {
                    const float s = (e < 4) ? S0[e & 3] : S1[e & 3];
                    const float den = fmaf(-2.f, s, q2e + k2r[e]);
                    const float pe = fast_exp2(s * s * fast_rcp(den) * isc);
                    lsum += pe;
                    p[e] = pe;
                }
            } else {
                #pragma unroll
                for (int e = 0; e < 8; ++e) {
                    const float s = (e < 4) ? S0[e & 3] : S1[e & 3];
                    const int j = jbase0 + (e >> 2) * 16 + (e & 3);
                    const float den = fmaf(-2.f, s, q2e + k2r[e]);
                    float pe = fast_exp2(s * s * fast_rcp(den) * isc);
                    pe = (j <= iM) ? pe : 0.f;
                    lsum += pe;
                    p[e] = pe;
                }
            }
            if (half) lsB += lsum; else lsA += lsum;

            // pack P -> bf16 hi (trunc) / lo (trunc of exact residual):
            // Ph+Pl ~= p to 2^-16; dropped Pl*vl term ~2^-17.
            // v_perm_b32 merges the two high-halves in one instruction.
            unsigned ph32[4], pl32[4];
            #pragma unroll
            for (int e2 = 0; e2 < 4; ++e2) {
                const unsigned b0 = __builtin_bit_cast(unsigned, p[e2 * 2]);
                const unsigned b1 = __builtin_bit_cast(unsigned, p[e2 * 2 + 1]);
                ph32[e2] = __builtin_amdgcn_perm(b1, b0, 0x07060302u);
                const float f0 = p[e2 * 2] -
                    __builtin_bit_cast(float, b0 & 0xFFFF0000u);
                const float f1 = p[e2 * 2 + 1] -
                    __builtin_bit_cast(float, b1 & 0xFFFF0000u);
                pl32[e2] = __builtin_amdgcn_perm(
                    __builtin_bit_cast(unsigned, f1),
                    __builtin_bit_cast(unsigned, f0), 0x07060302u);
            }
            const bf16x8 Ph = __builtin_bit_cast(bf16x8,
                (uintx4){ph32[0], ph32[1], ph32[2], ph32[3]});
            const bf16x8 Pl = __builtin_bit_cast(bf16x8,
                (uintx4){pl32[0], pl32[1], pl32[2], pl32[3]});

            floatx4 O = half ? OB : OA;
            __builtin_amdgcn_s_setprio(1);
            O = __builtin_amdgcn_mfma_f32_16x16x32_bf16(Ph, vh, O, 0, 0, 0);
            O = __builtin_amdgcn_mfma_f32_16x16x32_bf16(Pl, vh, O, 0, 0, 0);
            O = __builtin_amdgcn_mfma_f32_16x16x32_bf16(Ph, vl, O, 0, 0, 0);
            __builtin_amdgcn_s_setprio(0);
            if (half) OB = O; else OA = O;
        }
    }

    #pragma unroll
    for (int half = 0; half < 2; ++half) {
        float ls = half ? lsB : lsA;
        const floatx4 O = half ? OB : OA;
        const int ti = half ? tiB : tiA;
        ls += __shfl_xor(ls, 16, 64);
        ls += __shfl_xor(ls, 32, 64);
        const float linv = 1.0f / ls;
        #pragma unroll
        for (int r = 0; r < 4; ++r) {
            const float lr = __shfl(linv, quad * 4 + r, 16);
            const float v = O[r] * lr;
            const int i = ti * 16 + quad * 4 + r;
            const size_t off =
                ((size_t)(b * 1024 + i)) * 1024 + d * 16 + lane16;
            const unsigned short vh16 = f32_bf16(v);
            attn_h[off] = vh16;
            attn_l[off] = f32_bf16(v - bf16_f32(vh16));
            float s2 = v * v;
            s2 += __shfl_xor(s2, 1, 64);
            s2 += __shfl_xor(s2, 2, 64);
            s2 += __shfl_xor(s2, 4, 64);
            s2 += __shfl_xor(s2, 8, 64);
            if (lane16 == 0) atomicAdd(&x2a[b * 1024 + i], s2);
        }
    }
}

// ---------------------------------------------------------------------------
extern "C" void kernel_launch(void* const* d_in, const int* in_sizes, int n_in,
                              void* d_out, int out_size, void* d_ws, size_t ws_size,
                              hipStream_t stream)
{
    const float* x          = (const float*)d_in[0];
    // d_in[1] = causal mask, constant — causality hard-coded
    const float* w_qkv      = (const float*)d_in[2];
    const float* b_qkv      = (const float*)d_in[3];
    const float* alpha_qkv  = (const float*)d_in[4];
    const float* w_proj     = (const float*)d_in[5];
    const float* b_proj     = (const float*)d_in[6];
    const float* alpha_proj = (const float*)d_in[7];
    const float* alpha_attn = (const float*)d_in[8];
    float* out = (float*)d_out;

    float* ws = (float*)d_ws;
    unsigned short* KVU  = (unsigned short*)ws;                  // 6291456 f region
    unsigned short* WtQh = (unsigned short*)(ws + 6291456);      // 3072x1024 bf16 (permuted)
    unsigned short* WtQl = (unsigned short*)(ws + 7864320);
    unsigned short* WtPh = (unsigned short*)(ws + 9437184);      // 1024x1024 bf16
    unsigned short* WtPl = (unsigned short*)(ws + 9961472);
    unsigned short* xh   = (unsigned short*)(ws + 10485760);     // 2048x1024 bf16
    unsigned short* xl   = (unsigned short*)(ws + 11534336);
    float* x2x  = ws + 12582912;   // 2048
    float* x2a  = ws + 12584960;   // 2048 (atomic; zeroed by prep x-section)
    float* k2q  = ws + 12587008;   // 3072 (atomic)
    float* k2p  = ws + 12590080;   // 1024 (atomic)
    float* k2k  = ws + 12591104;   // 131072
    float* q2k  = ws + 12722176;   // 131072   (total 12853248 f = 51.4 MB)
    unsigned short* attn_h = WtQh;             // WtQ dead after QKV GEMM
    unsigned short* attn_l = WtQl;

    // zero atomic accumulators k2q,k2p (contiguous); x2a zeroed inside prep
    hipMemsetAsync(k2q, 0, (3072 + 1024) * sizeof(float), stream);

    // one merged prep dispatch: both weight transposes + x conversion
    prep_kernel<<<6144, 256, 0, stream>>>(
        x, w_qkv, w_proj, xh, xl, x2x, WtQh, WtQl, k2q, WtPh, WtPl, k2p, x2a);

    // QKV GEMM + fused Q/K/V pack (writes KVU, q2k, k2k directly)
    // 64x128 BK=64, minw=3 — CLOSED at 63.5us (see history)
    const float sb_qkv = sqrtf(3072.0f) / log1pf(3072.0f);
    gemm_yat_mfma_kernel<64, 128, 64, 2, 3><<<dim3(24, 32), 256, 0, stream>>>(
        xh, xl, WtQh, WtQl, b_qkv, x2x, k2q, alpha_qkv, nullptr,
        3072, 1024, sb_qkv, KVU, q2k, k2k);

    yat_attn_mfma2_kernel<<<dim3(64, 8, 2), 256, 0, stream>>>(
        KVU, k2k, q2k, alpha_attn, attn_h, attn_l, x2a);

    // proj: 64x64 BK=64, minw=2 (grid 512 = 2 blocks/CU)
    const float sb_proj = sqrtf(1024.0f) / log1pf(1024.0f);
    gemm_yat_mfma_kernel<64, 64, 64, 0, 2><<<dim3(16, 32), 256, 0, stream>>>(
        attn_h, attn_l, WtPh, WtPl, b_proj, x2a, k2p, alpha_proj, out,
        1024, 1024, sb_proj, nullptr, nullptr, nullptr);
}